// Round 1
// baseline (202.257 us; speedup 1.0000x reference)
//
#include <hip/hip_runtime.h>

typedef float f32x4 __attribute__((ext_vector_type(4)));
typedef short s16x8 __attribute__((ext_vector_type(8)));

#define SCALE 0.17677669529663687f
#define LOG2E 1.4426950408889634f

__device__ __forceinline__ unsigned short f2bf(float f) {
    unsigned u = __builtin_bit_cast(unsigned, f);
    u += 0x7fffu + ((u >> 16) & 1u);
    return (unsigned short)(u >> 16);
}

__device__ __forceinline__ float fexp2(float x) {
#if __has_builtin(__builtin_amdgcn_exp2f)
    return __builtin_amdgcn_exp2f(x);
#else
    return exp2f(x);
#endif
}

#define MFMA16(a, b, c) __builtin_amdgcn_mfma_f32_16x16x32_bf16((a), (b), (c), 0, 0, 0)

// ---------------------------------------------------------------------------
// K1: qkv projection.  qkv[o,t] = sum_c w_qkv[o,c] * x[b,c,s]
// grid (256 token-tiles of 64, 6 o-tiles of 64), block 256 (4 waves)
// Writes: Qb [bh][n][32] bf16 (pre-scaled by SCALE*LOG2E), Kb same, Vt [bh][32][n] bf16
// ---------------------------------------------------------------------------
__global__ __launch_bounds__(256) void k_qkv(const float* __restrict__ x,
                                             const float* __restrict__ w,
                                             unsigned short* __restrict__ Qb,
                                             unsigned short* __restrict__ Kb,
                                             unsigned short* __restrict__ Vt) {
    __shared__ unsigned short ldsT[64 * 136];  // x^T tile [64 tok][128 c], row pad->136 (272B, 16B aligned)
    const int tid = threadIdx.x;
    const int t0 = blockIdx.x * 64;  // flat token base (b*4096 + s)
    const int o0 = blockIdx.y * 64;
    const int b = t0 >> 12;
    const int s0 = t0 & 4095;

    // stage x^T tile as bf16 (coalesced global read, transposed LDS write)
    {
        const int t = tid & 63;
        const int cg = (tid >> 6) * 32;
        const float* xp = x + ((size_t)b * 128 + cg) * 4096 + s0 + t;
#pragma unroll
        for (int i = 0; i < 32; ++i)
            ldsT[t * 136 + cg + i] = f2bf(xp[(size_t)i * 4096]);
    }
    __syncthreads();

    const int lane = tid & 63;
    const int wv = tid >> 6;
    const int ln = lane & 15, lg = lane >> 4;
    const int ow = o0 + wv * 16;  // this wave's 16 output rows

    // A-frags from w (fp32 -> bf16 on the fly): row ow+ln, k = 32*ks + 8*lg + j
    s16x8 aW[4];
#pragma unroll
    for (int ks = 0; ks < 4; ++ks) {
        const float* wp = w + (size_t)(ow + ln) * 128 + ks * 32 + lg * 8;
        s16x8 a;
#pragma unroll
        for (int j = 0; j < 8; ++j) a[j] = (short)f2bf(wp[j]);
        aW[ks] = a;
    }

    f32x4 acc[4] = {{0, 0, 0, 0}, {0, 0, 0, 0}, {0, 0, 0, 0}, {0, 0, 0, 0}};
#pragma unroll
    for (int ts = 0; ts < 4; ++ts) {
#pragma unroll
        for (int ks = 0; ks < 4; ++ks) {
            s16x8 bx = *(const s16x8*)&ldsT[(ts * 16 + ln) * 136 + ks * 32 + lg * 8];
            acc[ts] = MFMA16(aW[ks], bx, acc[ts]);
        }
    }

    // epilogue: D row = ow + 4*lg + r, col token = t0 + 16*ts + ln
#pragma unroll
    for (int ts = 0; ts < 4; ++ts) {
        const int s = s0 + ts * 16 + ln;
#pragma unroll
        for (int r = 0; r < 4; ++r) {
            const int o = ow + lg * 4 + r;
            const float v = acc[ts][r];
            if (o < 128) {
                const int h = o >> 5, d = o & 31;
                Qb[((size_t)(b * 4 + h) * 4096 + s) * 32 + d] = f2bf(v * (SCALE * LOG2E));
            } else if (o < 256) {
                const int oo = o - 128, h = oo >> 5, d = oo & 31;
                Kb[((size_t)(b * 4 + h) * 4096 + s) * 32 + d] = f2bf(v);
            } else {
                const int oo = o - 256, h = oo >> 5, d = oo & 31;
                Vt[((size_t)(b * 4 + h) * 32 + d) * 4096 + s] = f2bf(v);
            }
        }
    }
}

// ---------------------------------------------------------------------------
// K2: fused attention (no online max needed: |logits| <~ 0.45 by construction).
// grid (64 q-tiles of 64, 16 bh), block 256 (4 waves, 16 q-rows each).
// Per 32-token step: 2 QK^T MFMAs -> exp2 -> rowsum accum -> P->bf16 -> per-wave
// LDS relayout (D-layout -> A-layout) -> 2 PV MFMAs.  Normalize once at end.
// Writes att [b][token][128] bf16 (channel = h*32+d).
// ---------------------------------------------------------------------------
__global__ __launch_bounds__(256) void k_attn(const unsigned short* __restrict__ Qb,
                                              const unsigned short* __restrict__ Kb,
                                              const unsigned short* __restrict__ Vt,
                                              unsigned short* __restrict__ att) {
    __shared__ unsigned short plds[4][16][32];  // per-wave P tile
    const int tid = threadIdx.x;
    const int lane = tid & 63;
    const int wv = tid >> 6;
    const int ln = lane & 15, lg = lane >> 4;
    const int bh = blockIdx.y;
    const int i0 = blockIdx.x * 64 + wv * 16;  // this wave's q rows
    const size_t base = (size_t)bh * 4096 * 32;

    // Q A-frag (K=d=32 -> loaded once)
    const s16x8 aQ = *(const s16x8*)(Qb + base + (size_t)(i0 + ln) * 32 + lg * 8);

    const unsigned short* kp = Kb + base + (size_t)ln * 32 + lg * 8;    // + j0*32
    const unsigned short* vp0 = Vt + base + (size_t)ln * 4096 + lg * 8;  // d = ln,    + j0
    const unsigned short* vp1 = vp0 + (size_t)16 * 4096;                 // d = 16+ln

    const f32x4 zf = {0.f, 0.f, 0.f, 0.f};
    f32x4 acc0 = zf, acc1 = zf;
    float lsum[4] = {0.f, 0.f, 0.f, 0.f};

    s16x8 bK0 = *(const s16x8*)(kp);
    s16x8 bK1 = *(const s16x8*)(kp + 16 * 32);
    s16x8 bV0 = *(const s16x8*)(vp0);
    s16x8 bV1 = *(const s16x8*)(vp1);

    for (int j0 = 0; j0 < 4096; j0 += 32) {
        s16x8 nK0 = bK0, nK1 = bK1, nV0 = bV0, nV1 = bV1;
        if (j0 + 32 < 4096) {  // prefetch next tile (L2-resident)
            nK0 = *(const s16x8*)(kp + (size_t)(j0 + 32) * 32);
            nK1 = *(const s16x8*)(kp + (size_t)(j0 + 48) * 32);
            nV0 = *(const s16x8*)(vp0 + j0 + 32);
            nV1 = *(const s16x8*)(vp1 + j0 + 32);
        }
        const f32x4 S0 = MFMA16(aQ, bK0, zf);
        const f32x4 S1 = MFMA16(aQ, bK1, zf);
        float p0[4], p1[4];
#pragma unroll
        for (int r = 0; r < 4; ++r) {
            p0[r] = fexp2(S0[r]);
            p1[r] = fexp2(S1[r]);
            lsum[r] += p0[r] + p1[r];
        }
        // D-layout (row=4lg+r, col=ln) -> LDS
#pragma unroll
        for (int r = 0; r < 4; ++r) {
            plds[wv][lg * 4 + r][ln] = f2bf(p0[r]);
            plds[wv][lg * 4 + r][ln + 16] = f2bf(p1[r]);
        }
        // intra-wave only: fence compiler + drain DS writes, no block barrier
        asm volatile("s_waitcnt lgkmcnt(0)" ::: "memory");
        const s16x8 aP = *(const s16x8*)&plds[wv][ln][lg * 8];
        acc0 = MFMA16(aP, bV0, acc0);
        acc1 = MFMA16(aP, bV1, acc1);
        bK0 = nK0; bK1 = nK1; bV0 = nV0; bV1 = nV1;
    }

    // normalize: rowsum reduce across the 16 lanes of each lane-group
    const int b = bh >> 2, h = bh & 3;
#pragma unroll
    for (int r = 0; r < 4; ++r) {
        float s = lsum[r];
        s += __shfl_xor(s, 1);
        s += __shfl_xor(s, 2);
        s += __shfl_xor(s, 4);
        s += __shfl_xor(s, 8);
        const float rinv = 1.0f / s;
        const int i = i0 + lg * 4 + r;
        const size_t rowoff = ((size_t)b * 4096 + i) * 128 + h * 32;
        att[rowoff + ln] = f2bf(acc0[r] * rinv);
        att[rowoff + 16 + ln] = f2bf(acc1[r] * rinv);
    }
}

// ---------------------------------------------------------------------------
// K3: out projection.  out[b,o,s] = sum_c w_out[o,c]*att[b,s,c] + b_out[o]
// grid (256 token-tiles of 64, 2 o-tiles of 64), block 256 (4 waves).
// att is [tok][c] bf16 -> B-frags are contiguous 16B global reads, no LDS.
// ---------------------------------------------------------------------------
__global__ __launch_bounds__(256) void k_out(const unsigned short* __restrict__ att,
                                             const float* __restrict__ w,
                                             const float* __restrict__ bias,
                                             float* __restrict__ out) {
    const int tid = threadIdx.x;
    const int lane = tid & 63;
    const int wv = tid >> 6;
    const int ln = lane & 15, lg = lane >> 4;
    const int t0 = blockIdx.x * 64;
    const int o0 = blockIdx.y * 64;
    const int ow = o0 + wv * 16;
    const int b = t0 >> 12, s0 = t0 & 4095;

    s16x8 aW[4];
#pragma unroll
    for (int ks = 0; ks < 4; ++ks) {
        const float* wp = w + (size_t)(ow + ln) * 128 + ks * 32 + lg * 8;
        s16x8 a;
#pragma unroll
        for (int j = 0; j < 8; ++j) a[j] = (short)f2bf(wp[j]);
        aW[ks] = a;
    }

    f32x4 acc[4] = {{0, 0, 0, 0}, {0, 0, 0, 0}, {0, 0, 0, 0}, {0, 0, 0, 0}};
#pragma unroll
    for (int ts = 0; ts < 4; ++ts) {
#pragma unroll
        for (int ks = 0; ks < 4; ++ks) {
            s16x8 bx = *(const s16x8*)(att + ((size_t)t0 + ts * 16 + ln) * 128 + ks * 32 + lg * 8);
            acc[ts] = MFMA16(aW[ks], bx, acc[ts]);
        }
    }

#pragma unroll
    for (int ts = 0; ts < 4; ++ts) {
        const int s = s0 + ts * 16 + ln;
#pragma unroll
        for (int r = 0; r < 4; ++r) {
            const int o = ow + lg * 4 + r;
            out[((size_t)b * 128 + o) * 4096 + s] = acc[ts][r] + bias[o];
        }
    }
}

// ---------------------------------------------------------------------------
extern "C" void kernel_launch(void* const* d_in, const int* in_sizes, int n_in,
                              void* d_out, int out_size, void* d_ws, size_t ws_size,
                              hipStream_t stream) {
    const float* x = (const float*)d_in[0];      // [4,128,64,64]
    const float* w_qkv = (const float*)d_in[1];  // [384,128]
    const float* w_out = (const float*)d_in[2];  // [128,128]
    const float* b_out = (const float*)d_in[3];  // [128]
    float* out = (float*)d_out;                  // [4,128,64,64]

    unsigned short* Qb = (unsigned short*)d_ws;                 // 16*4096*32 bf16 = 4 MiB
    unsigned short* Kb = Qb + (size_t)16 * 4096 * 32;           // 4 MiB
    unsigned short* Vt = Kb + (size_t)16 * 4096 * 32;           // 4 MiB ([bh][32][n])
    unsigned short* att = Vt + (size_t)16 * 4096 * 32;          // 4 MiB ([b][n][128])

    k_qkv<<<dim3(256, 6), 256, 0, stream>>>(x, w_qkv, Qb, Kb, Vt);
    k_attn<<<dim3(64, 16), 256, 0, stream>>>(Qb, Kb, Vt, att);
    k_out<<<dim3(256, 2), 256, 0, stream>>>(att, w_out, b_out, out);
}

// Round 2
// 201.653 us; speedup vs baseline: 1.0030x; 1.0030x over previous
//
#include <hip/hip_runtime.h>

typedef float f32x4 __attribute__((ext_vector_type(4)));
typedef short s16x8 __attribute__((ext_vector_type(8)));
typedef unsigned int u32;
typedef unsigned int u32x4 __attribute__((ext_vector_type(4)));

#define SCALE 0.17677669529663687f
#define LOG2E 1.4426950408889634f

__device__ __forceinline__ unsigned short f2bf(float f) {
    unsigned u = __builtin_bit_cast(unsigned, f);
    u += 0x7fffu + ((u >> 16) & 1u);
    return (unsigned short)(u >> 16);
}

__device__ __forceinline__ float fexp2(float x) {
#if __has_builtin(__builtin_amdgcn_exp2f)
    return __builtin_amdgcn_exp2f(x);
#else
    return exp2f(x);
#endif
}

// packed f32 pair -> bf16x2 (RNE), dst.lo = lo
__device__ __forceinline__ u32 cvtpk(float lo, float hi) {
    u32 r;
    asm("v_cvt_pk_bf16_f32 %0, %1, %2" : "=v"(r) : "v"(lo), "v"(hi));
    return r;
}

// swaps a.hi32lanes <-> b.lo32lanes:  a' = [a.lo, b.lo], b' = [a.hi, b.hi]
__device__ __forceinline__ void pl32swap(u32& a, u32& b) {
    asm("v_permlane32_swap_b32 %0, %1" : "+v"(a), "+v"(b));
}

#define MFMA16(a, b, c) __builtin_amdgcn_mfma_f32_16x16x32_bf16((a), (b), (c), 0, 0, 0)

// ---------------------------------------------------------------------------
// K1: qkv projection (unchanged).
// ---------------------------------------------------------------------------
__global__ __launch_bounds__(256) void k_qkv(const float* __restrict__ x,
                                             const float* __restrict__ w,
                                             unsigned short* __restrict__ Qb,
                                             unsigned short* __restrict__ Kb,
                                             unsigned short* __restrict__ Vt) {
    __shared__ unsigned short ldsT[64 * 136];
    const int tid = threadIdx.x;
    const int t0 = blockIdx.x * 64;
    const int o0 = blockIdx.y * 64;
    const int b = t0 >> 12;
    const int s0 = t0 & 4095;

    {
        const int t = tid & 63;
        const int cg = (tid >> 6) * 32;
        const float* xp = x + ((size_t)b * 128 + cg) * 4096 + s0 + t;
#pragma unroll
        for (int i = 0; i < 32; ++i)
            ldsT[t * 136 + cg + i] = f2bf(xp[(size_t)i * 4096]);
    }
    __syncthreads();

    const int lane = tid & 63;
    const int wv = tid >> 6;
    const int ln = lane & 15, lg = lane >> 4;
    const int ow = o0 + wv * 16;

    s16x8 aW[4];
#pragma unroll
    for (int ks = 0; ks < 4; ++ks) {
        const float* wp = w + (size_t)(ow + ln) * 128 + ks * 32 + lg * 8;
        s16x8 a;
#pragma unroll
        for (int j = 0; j < 8; ++j) a[j] = (short)f2bf(wp[j]);
        aW[ks] = a;
    }

    f32x4 acc[4] = {{0, 0, 0, 0}, {0, 0, 0, 0}, {0, 0, 0, 0}, {0, 0, 0, 0}};
#pragma unroll
    for (int ts = 0; ts < 4; ++ts) {
#pragma unroll
        for (int ks = 0; ks < 4; ++ks) {
            s16x8 bx = *(const s16x8*)&ldsT[(ts * 16 + ln) * 136 + ks * 32 + lg * 8];
            acc[ts] = MFMA16(aW[ks], bx, acc[ts]);
        }
    }

#pragma unroll
    for (int ts = 0; ts < 4; ++ts) {
        const int s = s0 + ts * 16 + ln;
#pragma unroll
        for (int r = 0; r < 4; ++r) {
            const int o = ow + lg * 4 + r;
            const float v = acc[ts][r];
            if (o < 128) {
                const int h = o >> 5, d = o & 31;
                Qb[((size_t)(b * 4 + h) * 4096 + s) * 32 + d] = f2bf(v * (SCALE * LOG2E));
            } else if (o < 256) {
                const int oo = o - 128, h = oo >> 5, d = oo & 31;
                Kb[((size_t)(b * 4 + h) * 4096 + s) * 32 + d] = f2bf(v);
            } else {
                const int oo = o - 256, h = oo >> 5, d = oo & 31;
                Vt[((size_t)(b * 4 + h) * 32 + d) * 4096 + s] = f2bf(v);
            }
        }
    }
}

// ---------------------------------------------------------------------------
// K2: fused attention, swapped-QK^T + fully in-register P relayout.
// grid (64 q-tiles of 64, 16 bh), block 512 (8 waves).
// Waves 0-3: keys [0,2048); waves 4-7: keys [2048,4096); same q rows.
// Per 32-key step: 2 QK MFMAs (S^T = mfma(K,Q), P-row lane-local) -> exp2 ->
// cvt_pk -> shfl_xor(16)+cndmask -> permlane32_swap -> A-frag -> 2 PV MFMAs.
// No LDS in the loop; K-halves combined via LDS once at the end.
// ---------------------------------------------------------------------------
__global__ __launch_bounds__(512) void k_attn(const unsigned short* __restrict__ Qb,
                                              const unsigned short* __restrict__ Kb,
                                              const unsigned short* __restrict__ Vt,
                                              unsigned short* __restrict__ att) {
    __shared__ float comb[4][64][9];  // upper-half waves' partials (9216 B)
    const int tid = threadIdx.x;
    const int lane = tid & 63;
    const int wv = tid >> 6;  // 0..7
    const int ln = lane & 15, lg = lane >> 4;
    const bool ev = (lane & 16) == 0;  // lg0 / lg2
    const int bh = blockIdx.y;
    const int i0 = blockIdx.x * 64 + (wv & 3) * 16;  // this wave's 16 q rows
    const int khalf = wv >> 2;
    const size_t base = (size_t)bh * 4096 * 32;

    // B-frag Q: lane holds Q[i0+ln][8lg+m]  (pre-scaled by SCALE*LOG2E)
    const s16x8 bQ = *(const s16x8*)(Qb + base + (size_t)(i0 + ln) * 32 + lg * 8);

    const int j0 = khalf * 2048;
    const unsigned short* kp = Kb + base + (size_t)(j0 + ln) * 32 + lg * 8;
    const unsigned short* vp = Vt + base + (size_t)ln * 4096 + lg * 8 + j0;

    const f32x4 zf = {0.f, 0.f, 0.f, 0.f};
    f32x4 acc0 = zf, acc1 = zf;
    float lsum = 0.f;

    s16x8 K0 = *(const s16x8*)(kp);
    s16x8 K1 = *(const s16x8*)(kp + 16 * 32);
    s16x8 V0 = *(const s16x8*)(vp);
    s16x8 V1 = *(const s16x8*)(vp + 16 * 4096);

    auto body = [&](s16x8 cK0, s16x8 cK1, s16x8 cV0, s16x8 cV1) {
        // S^T: lane(ln,lg) reg r = S[q=i0+ln][j = jt + 4lg + r] (S0), +16 (S1)
        const f32x4 S0 = MFMA16(cK0, bQ, zf);
        const f32x4 S1 = MFMA16(cK1, bQ, zf);
        float p0[4], p1[4];
#pragma unroll
        for (int r = 0; r < 4; ++r) {
            p0[r] = fexp2(S0[r]);
            p1[r] = fexp2(S1[r]);
        }
        lsum += ((p0[0] + p0[1]) + (p0[2] + p0[3])) + ((p1[0] + p1[1]) + (p1[2] + p1[3]));
        // pack: c0/c1 = keys (4lg+0,1),(4lg+2,3); c2/c3 = same +16
        u32 c0 = cvtpk(p0[0], p0[1]), c1 = cvtpk(p0[2], p0[3]);
        u32 c2 = cvtpk(p1[0], p1[1]), c3 = cvtpk(p1[2], p1[3]);
        // partner (lg^1) values
        u32 s0 = (u32)__shfl_xor((int)c0, 16);
        u32 s1 = (u32)__shfl_xor((int)c1, 16);
        u32 s2 = (u32)__shfl_xor((int)c2, 16);
        u32 s3 = (u32)__shfl_xor((int)c3, 16);
        // mirrored quads: even lg: [c,c,s,s]; odd lg: [s,s,c,c]
        u32 y00 = ev ? c0 : s0, y01 = ev ? c1 : s1, y02 = ev ? s0 : c0, y03 = ev ? s1 : c1;
        u32 y10 = ev ? c2 : s2, y11 = ev ? c3 : s3, y12 = ev ? s2 : c2, y13 = ev ? s3 : c3;
        // after swap: y0k = [Y0.lo, Y1.lo] (for lg0/lg2), y1k = [Y0.hi, Y1.hi] (for lg1/lg3)
        pl32swap(y00, y10);
        pl32swap(y01, y11);
        pl32swap(y02, y12);
        pl32swap(y03, y13);
        u32x4 apv;
        apv.x = ev ? y00 : y10;
        apv.y = ev ? y01 : y11;
        apv.z = ev ? y02 : y12;
        apv.w = ev ? y03 : y13;
        const s16x8 aP = __builtin_bit_cast(s16x8, apv);
        // PV: D[4lg+r][ln] = out[q=i0+4lg+r][d=ln (acc0) / 16+ln (acc1)]
        acc0 = MFMA16(aP, cV0, acc0);
        acc1 = MFMA16(aP, cV1, acc1);
    };

    for (int it = 0; it < 63; ++it) {
        kp += 32 * 32;
        vp += 32;
        s16x8 nK0 = *(const s16x8*)(kp);
        s16x8 nK1 = *(const s16x8*)(kp + 16 * 32);
        s16x8 nV0 = *(const s16x8*)(vp);
        s16x8 nV1 = *(const s16x8*)(vp + 16 * 4096);
        body(K0, K1, V0, V1);
        K0 = nK0; K1 = nK1; V0 = nV0; V1 = nV1;
    }
    body(K0, K1, V0, V1);

    // ---- combine the two K-halves ----
    if (wv >= 4) {
        float* p = &comb[wv - 4][lane][0];
        p[0] = acc0[0]; p[1] = acc0[1]; p[2] = acc0[2]; p[3] = acc0[3];
        p[4] = acc1[0]; p[5] = acc1[1]; p[6] = acc1[2]; p[7] = acc1[3];
        p[8] = lsum;
    }
    __syncthreads();
    if (wv < 4) {
        const float* p = &comb[wv][lane][0];
        acc0[0] += p[0]; acc0[1] += p[1]; acc0[2] += p[2]; acc0[3] += p[3];
        acc1[0] += p[4]; acc1[1] += p[5]; acc1[2] += p[6]; acc1[3] += p[7];
        lsum += p[8];
        // full row sums: reduce over lg groups -> every lane has total for q=i0+ln
        lsum += __shfl_xor(lsum, 16);
        lsum += __shfl_xor(lsum, 32);
        const int b = bh >> 2, h = bh & 3;
#pragma unroll
        for (int r = 0; r < 4; ++r) {
            const float rs = __shfl(lsum, 4 * lg + r);  // sum for q row 4lg+r
            const float rinv = 1.0f / rs;
            const int q = i0 + lg * 4 + r;
            const size_t rowoff = ((size_t)b * 4096 + q) * 128 + h * 32;
            att[rowoff + ln] = f2bf(acc0[r] * rinv);
            att[rowoff + 16 + ln] = f2bf(acc1[r] * rinv);
        }
    }
}

// ---------------------------------------------------------------------------
// K3: out projection (unchanged).
// ---------------------------------------------------------------------------
__global__ __launch_bounds__(256) void k_out(const unsigned short* __restrict__ att,
                                             const float* __restrict__ w,
                                             const float* __restrict__ bias,
                                             float* __restrict__ out) {
    const int tid = threadIdx.x;
    const int lane = tid & 63;
    const int wv = tid >> 6;
    const int ln = lane & 15, lg = lane >> 4;
    const int t0 = blockIdx.x * 64;
    const int o0 = blockIdx.y * 64;
    const int ow = o0 + wv * 16;
    const int b = t0 >> 12, s0 = t0 & 4095;

    s16x8 aW[4];
#pragma unroll
    for (int ks = 0; ks < 4; ++ks) {
        const float* wp = w + (size_t)(ow + ln) * 128 + ks * 32 + lg * 8;
        s16x8 a;
#pragma unroll
        for (int j = 0; j < 8; ++j) a[j] = (short)f2bf(wp[j]);
        aW[ks] = a;
    }

    f32x4 acc[4] = {{0, 0, 0, 0}, {0, 0, 0, 0}, {0, 0, 0, 0}, {0, 0, 0, 0}};
#pragma unroll
    for (int ts = 0; ts < 4; ++ts) {
#pragma unroll
        for (int ks = 0; ks < 4; ++ks) {
            s16x8 bx = *(const s16x8*)(att + ((size_t)t0 + ts * 16 + ln) * 128 + ks * 32 + lg * 8);
            acc[ts] = MFMA16(aW[ks], bx, acc[ts]);
        }
    }

#pragma unroll
    for (int ts = 0; ts < 4; ++ts) {
        const int s = s0 + ts * 16 + ln;
#pragma unroll
        for (int r = 0; r < 4; ++r) {
            const int o = ow + lg * 4 + r;
            out[((size_t)b * 128 + o) * 4096 + s] = acc[ts][r] + bias[o];
        }
    }
}

// ---------------------------------------------------------------------------
extern "C" void kernel_launch(void* const* d_in, const int* in_sizes, int n_in,
                              void* d_out, int out_size, void* d_ws, size_t ws_size,
                              hipStream_t stream) {
    const float* x = (const float*)d_in[0];
    const float* w_qkv = (const float*)d_in[1];
    const float* w_out = (const float*)d_in[2];
    const float* b_out = (const float*)d_in[3];
    float* out = (float*)d_out;

    unsigned short* Qb = (unsigned short*)d_ws;
    unsigned short* Kb = Qb + (size_t)16 * 4096 * 32;
    unsigned short* Vt = Kb + (size_t)16 * 4096 * 32;
    unsigned short* att = Vt + (size_t)16 * 4096 * 32;

    k_qkv<<<dim3(256, 6), 256, 0, stream>>>(x, w_qkv, Qb, Kb, Vt);
    k_attn<<<dim3(64, 16), 512, 0, stream>>>(Qb, Kb, Vt, att);
    k_out<<<dim3(256, 2), 256, 0, stream>>>(att, w_out, b_out, out);
}

// Round 8
// 120.255 us; speedup vs baseline: 1.6819x; 1.6769x over previous
//
#include <hip/hip_runtime.h>

typedef float f32x4 __attribute__((ext_vector_type(4)));
typedef short s16x8 __attribute__((ext_vector_type(8)));
typedef unsigned int u32;
typedef unsigned int u32x4 __attribute__((ext_vector_type(4)));

#define SCALE 0.17677669529663687f
#define LOG2E 1.4426950408889634f

__device__ __forceinline__ unsigned short f2bf(float f) {
    unsigned u = __builtin_bit_cast(unsigned, f);
    u += 0x7fffu + ((u >> 16) & 1u);
    return (unsigned short)(u >> 16);
}

__device__ __forceinline__ float fexp2(float x) {
#if __has_builtin(__builtin_amdgcn_exp2f)
    return __builtin_amdgcn_exp2f(x);
#else
    return exp2f(x);
#endif
}

// packed f32 pair -> bf16x2 (RNE), dst.lo = lo
__device__ __forceinline__ u32 cvtpk(float lo, float hi) {
    u32 r;
    asm("v_cvt_pk_bf16_f32 %0, %1, %2" : "=v"(r) : "v"(lo), "v"(hi));
    return r;
}

// swaps a.hi32lanes <-> b.lo32lanes:  a' = [a.lo, b.lo], b' = [a.hi, b.hi]
__device__ __forceinline__ void pl32swap(u32& a, u32& b) {
    asm("v_permlane32_swap_b32 %0, %1" : "+v"(a), "+v"(b));
}

#define MFMA16(a, b, c) __builtin_amdgcn_mfma_f32_16x16x32_bf16((a), (b), (c), 0, 0, 0)

// ---------------------------------------------------------------------------
// K1: qkv projection.  Writes Q/K as [bh][tok][32] bf16 (Q pre-scaled).
// V is written in MFMA-B-fragment-major order:
//   Vf[bh][jb][dhalf][lane][t] = V[token = jb*32 + 8*(lane>>4) + t][d = dhalf*16 + (lane&15)]
// so k_attn's per-32-key V loads are contiguous 1KB wave reads.
// ---------------------------------------------------------------------------
__global__ __launch_bounds__(256) void k_qkv(const float* __restrict__ x,
                                             const float* __restrict__ w,
                                             unsigned short* __restrict__ Qb,
                                             unsigned short* __restrict__ Kb,
                                             unsigned short* __restrict__ Vf) {
    __shared__ unsigned short ldsT[64 * 136];
    const int tid = threadIdx.x;
    const int t0 = blockIdx.x * 64;
    const int o0 = blockIdx.y * 64;
    const int b = t0 >> 12;
    const int s0 = t0 & 4095;

    {
        const int t = tid & 63;
        const int cg = (tid >> 6) * 32;
        const float* xp = x + ((size_t)b * 128 + cg) * 4096 + s0 + t;
#pragma unroll
        for (int i = 0; i < 32; ++i)
            ldsT[t * 136 + cg + i] = f2bf(xp[(size_t)i * 4096]);
    }
    __syncthreads();

    const int lane = tid & 63;
    const int wv = tid >> 6;
    const int ln = lane & 15, lg = lane >> 4;
    const int ow = o0 + wv * 16;

    s16x8 aW[4];
#pragma unroll
    for (int ks = 0; ks < 4; ++ks) {
        const float* wp = w + (size_t)(ow + ln) * 128 + ks * 32 + lg * 8;
        s16x8 a;
#pragma unroll
        for (int j = 0; j < 8; ++j) a[j] = (short)f2bf(wp[j]);
        aW[ks] = a;
    }

    f32x4 acc[4] = {{0, 0, 0, 0}, {0, 0, 0, 0}, {0, 0, 0, 0}, {0, 0, 0, 0}};
#pragma unroll
    for (int ts = 0; ts < 4; ++ts) {
#pragma unroll
        for (int ks = 0; ks < 4; ++ks) {
            s16x8 bx = *(const s16x8*)&ldsT[(ts * 16 + ln) * 136 + ks * 32 + lg * 8];
            acc[ts] = MFMA16(aW[ks], bx, acc[ts]);
        }
    }

#pragma unroll
    for (int ts = 0; ts < 4; ++ts) {
        const int s = s0 + ts * 16 + ln;
#pragma unroll
        for (int r = 0; r < 4; ++r) {
            const int o = ow + lg * 4 + r;
            const float v = acc[ts][r];
            if (o < 128) {
                const int h = o >> 5, d = o & 31;
                Qb[((size_t)(b * 4 + h) * 4096 + s) * 32 + d] = f2bf(v * (SCALE * LOG2E));
            } else if (o < 256) {
                const int oo = o - 128, h = oo >> 5, d = oo & 31;
                Kb[((size_t)(b * 4 + h) * 4096 + s) * 32 + d] = f2bf(v);
            } else {
                const int oo = o - 256, h = oo >> 5, d = oo & 31;
                const int bh = b * 4 + h;
                const int jb = s >> 5, js = s & 31;
                const int lanep = (js >> 3) * 16 + (d & 15);
                const size_t idx = ((((size_t)bh * 128 + jb) * 2 + (d >> 4)) * 64 + lanep) * 8 + (js & 7);
                Vf[idx] = f2bf(v);
            }
        }
    }
}

// ---------------------------------------------------------------------------
// K2: fused attention, swapped-QK^T + fully in-register P relayout.
// Identical to the passing R2 kernel EXCEPT the V loads now read the
// fragment-major Vf layout (contiguous 1KB per wave per load).
// grid (64 q-tiles of 64, 16 bh), block 512 (8 waves).
// Waves 0-3: keys [0,2048); waves 4-7: keys [2048,4096); same q rows.
// ---------------------------------------------------------------------------
__global__ __launch_bounds__(512) void k_attn(const unsigned short* __restrict__ Qb,
                                              const unsigned short* __restrict__ Kb,
                                              const unsigned short* __restrict__ Vf,
                                              unsigned short* __restrict__ att) {
    __shared__ float comb[4][64][9];  // upper-half waves' partials (9216 B)
    const int tid = threadIdx.x;
    const int lane = tid & 63;
    const int wv = tid >> 6;  // 0..7
    const int ln = lane & 15, lg = lane >> 4;
    const bool ev = (lane & 16) == 0;  // lg0 / lg2
    const int bh = blockIdx.y;
    const int i0 = blockIdx.x * 64 + (wv & 3) * 16;  // this wave's 16 q rows
    const int khalf = wv >> 2;
    const size_t base = (size_t)bh * 4096 * 32;

    // B-frag Q: lane holds Q[i0+ln][8lg+m]  (pre-scaled by SCALE*LOG2E)
    const s16x8 bQ = *(const s16x8*)(Qb + base + (size_t)(i0 + ln) * 32 + lg * 8);

    const int j0 = khalf * 2048;
    const unsigned short* kp = Kb + base + (size_t)(j0 + ln) * 32 + lg * 8;
    // Vf: [bh][jb][dhalf][lane][t]; this wave starts at jb = khalf*64
    const unsigned short* vp = Vf + (size_t)bh * 131072 + (size_t)(khalf * 64) * 1024 + lane * 8;

    const f32x4 zf = {0.f, 0.f, 0.f, 0.f};
    f32x4 acc0 = zf, acc1 = zf;
    float lsum = 0.f;

    s16x8 K0 = *(const s16x8*)(kp);
    s16x8 K1 = *(const s16x8*)(kp + 16 * 32);
    s16x8 V0 = *(const s16x8*)(vp);        // d = ln
    s16x8 V1 = *(const s16x8*)(vp + 512);  // d = 16+ln

    auto body = [&](s16x8 cK0, s16x8 cK1, s16x8 cV0, s16x8 cV1) {
        // S^T: lane(ln,lg) reg r = S[q=i0+ln][j = jt + 4lg + r] (S0), +16 (S1)
        const f32x4 S0 = MFMA16(cK0, bQ, zf);
        const f32x4 S1 = MFMA16(cK1, bQ, zf);
        float p0[4], p1[4];
#pragma unroll
        for (int r = 0; r < 4; ++r) {
            p0[r] = fexp2(S0[r]);
            p1[r] = fexp2(S1[r]);
        }
        lsum += ((p0[0] + p0[1]) + (p0[2] + p0[3])) + ((p1[0] + p1[1]) + (p1[2] + p1[3]));
        // pack: c0/c1 = keys (4lg+0,1),(4lg+2,3); c2/c3 = same +16
        u32 c0 = cvtpk(p0[0], p0[1]), c1 = cvtpk(p0[2], p0[3]);
        u32 c2 = cvtpk(p1[0], p1[1]), c3 = cvtpk(p1[2], p1[3]);
        // partner (lg^1) values
        u32 s0 = (u32)__shfl_xor((int)c0, 16);
        u32 s1 = (u32)__shfl_xor((int)c1, 16);
        u32 s2 = (u32)__shfl_xor((int)c2, 16);
        u32 s3 = (u32)__shfl_xor((int)c3, 16);
        // mirrored quads: even lg: [c,c,s,s]; odd lg: [s,s,c,c]
        u32 y00 = ev ? c0 : s0, y01 = ev ? c1 : s1, y02 = ev ? s0 : c0, y03 = ev ? s1 : c1;
        u32 y10 = ev ? c2 : s2, y11 = ev ? c3 : s3, y12 = ev ? s2 : c2, y13 = ev ? s3 : c3;
        // after swap: y0k = [Y0.lo, Y1.lo] (for lg0/lg2), y1k = [Y0.hi, Y1.hi] (for lg1/lg3)
        pl32swap(y00, y10);
        pl32swap(y01, y11);
        pl32swap(y02, y12);
        pl32swap(y03, y13);
        u32x4 apv;
        apv.x = ev ? y00 : y10;
        apv.y = ev ? y01 : y11;
        apv.z = ev ? y02 : y12;
        apv.w = ev ? y03 : y13;
        const s16x8 aP = __builtin_bit_cast(s16x8, apv);
        // PV: D[4lg+r][ln] = out[q=i0+4lg+r][d=ln (acc0) / 16+ln (acc1)]
        acc0 = MFMA16(aP, cV0, acc0);
        acc1 = MFMA16(aP, cV1, acc1);
    };

    for (int it = 0; it < 63; ++it) {
        kp += 32 * 32;
        vp += 1024;
        s16x8 nK0 = *(const s16x8*)(kp);
        s16x8 nK1 = *(const s16x8*)(kp + 16 * 32);
        s16x8 nV0 = *(const s16x8*)(vp);
        s16x8 nV1 = *(const s16x8*)(vp + 512);
        body(K0, K1, V0, V1);
        K0 = nK0; K1 = nK1; V0 = nV0; V1 = nV1;
    }
    body(K0, K1, V0, V1);

    // ---- combine the two K-halves ----
    if (wv >= 4) {
        float* p = &comb[wv - 4][lane][0];
        p[0] = acc0[0]; p[1] = acc0[1]; p[2] = acc0[2]; p[3] = acc0[3];
        p[4] = acc1[0]; p[5] = acc1[1]; p[6] = acc1[2]; p[7] = acc1[3];
        p[8] = lsum;
    }
    __syncthreads();
    if (wv < 4) {
        const float* p = &comb[wv][lane][0];
        acc0[0] += p[0]; acc0[1] += p[1]; acc0[2] += p[2]; acc0[3] += p[3];
        acc1[0] += p[4]; acc1[1] += p[5]; acc1[2] += p[6]; acc1[3] += p[7];
        lsum += p[8];
        // full row sums: reduce over lg groups -> every lane has total for q=i0+ln
        lsum += __shfl_xor(lsum, 16);
        lsum += __shfl_xor(lsum, 32);
        const int b = bh >> 2, h = bh & 3;
#pragma unroll
        for (int r = 0; r < 4; ++r) {
            const float rs = __shfl(lsum, 4 * lg + r);  // sum for q row 4lg+r
            const float rinv = 1.0f / rs;
            const int q = i0 + lg * 4 + r;
            const size_t rowoff = ((size_t)b * 4096 + q) * 128 + h * 32;
            att[rowoff + ln] = f2bf(acc0[r] * rinv);
            att[rowoff + 16 + ln] = f2bf(acc1[r] * rinv);
        }
    }
}

// ---------------------------------------------------------------------------
// K3: out projection (unchanged).
// ---------------------------------------------------------------------------
__global__ __launch_bounds__(256) void k_out(const unsigned short* __restrict__ att,
                                             const float* __restrict__ w,
                                             const float* __restrict__ bias,
                                             float* __restrict__ out) {
    const int tid = threadIdx.x;
    const int lane = tid & 63;
    const int wv = tid >> 6;
    const int ln = lane & 15, lg = lane >> 4;
    const int t0 = blockIdx.x * 64;
    const int o0 = blockIdx.y * 64;
    const int ow = o0 + wv * 16;
    const int b = t0 >> 12, s0 = t0 & 4095;

    s16x8 aW[4];
#pragma unroll
    for (int ks = 0; ks < 4; ++ks) {
        const float* wp = w + (size_t)(ow + ln) * 128 + ks * 32 + lg * 8;
        s16x8 a;
#pragma unroll
        for (int j = 0; j < 8; ++j) a[j] = (short)f2bf(wp[j]);
        aW[ks] = a;
    }

    f32x4 acc[4] = {{0, 0, 0, 0}, {0, 0, 0, 0}, {0, 0, 0, 0}, {0, 0, 0, 0}};
#pragma unroll
    for (int ts = 0; ts < 4; ++ts) {
#pragma unroll
        for (int ks = 0; ks < 4; ++ks) {
            s16x8 bx = *(const s16x8*)(att + ((size_t)t0 + ts * 16 + ln) * 128 + ks * 32 + lg * 8);
            acc[ts] = MFMA16(aW[ks], bx, acc[ts]);
        }
    }

#pragma unroll
    for (int ts = 0; ts < 4; ++ts) {
        const int s = s0 + ts * 16 + ln;
#pragma unroll
        for (int r = 0; r < 4; ++r) {
            const int o = ow + lg * 4 + r;
            out[((size_t)b * 128 + o) * 4096 + s] = acc[ts][r] + bias[o];
        }
    }
}

// ---------------------------------------------------------------------------
extern "C" void kernel_launch(void* const* d_in, const int* in_sizes, int n_in,
                              void* d_out, int out_size, void* d_ws, size_t ws_size,
                              hipStream_t stream) {
    const float* x = (const float*)d_in[0];
    const float* w_qkv = (const float*)d_in[1];
    const float* w_out = (const float*)d_in[2];
    const float* b_out = (const float*)d_in[3];
    float* out = (float*)d_out;

    unsigned short* Qb = (unsigned short*)d_ws;               // 4 MiB
    unsigned short* Kb = Qb + (size_t)16 * 4096 * 32;         // 4 MiB
    unsigned short* Vf = Kb + (size_t)16 * 4096 * 32;         // 4 MiB (fragment-major)
    unsigned short* att = Vf + (size_t)16 * 4096 * 32;        // 4 MiB

    k_qkv<<<dim3(256, 6), 256, 0, stream>>>(x, w_qkv, Qb, Kb, Vf);
    k_attn<<<dim3(64, 16), 512, 0, stream>>>(Qb, Kb, Vf, att);
    k_out<<<dim3(256, 2), 256, 0, stream>>>(att, w_out, b_out, out);
}

// Round 10
// 119.908 us; speedup vs baseline: 1.6868x; 1.0029x over previous
//
#include <hip/hip_runtime.h>

typedef float f32x4 __attribute__((ext_vector_type(4)));
typedef short s16x8 __attribute__((ext_vector_type(8)));
typedef unsigned int u32;
typedef unsigned int u32x4 __attribute__((ext_vector_type(4)));

#define SCALE 0.17677669529663687f
#define LOG2E 1.4426950408889634f

__device__ __forceinline__ unsigned short f2bf(float f) {
    unsigned u = __builtin_bit_cast(unsigned, f);
    u += 0x7fffu + ((u >> 16) & 1u);
    return (unsigned short)(u >> 16);
}

__device__ __forceinline__ float fexp2(float x) {
#if __has_builtin(__builtin_amdgcn_exp2f)
    return __builtin_amdgcn_exp2f(x);
#else
    return exp2f(x);
#endif
}

// packed f32 pair -> bf16x2 (RNE), dst.lo = lo
__device__ __forceinline__ u32 cvtpk(float lo, float hi) {
    u32 r;
    asm("v_cvt_pk_bf16_f32 %0, %1, %2" : "=v"(r) : "v"(lo), "v"(hi));
    return r;
}

#define MFMA16(a, b, c) __builtin_amdgcn_mfma_f32_16x16x32_bf16((a), (b), (c), 0, 0, 0)

// ---------------------------------------------------------------------------
// K1: qkv projection.  Q as [bh][tok][32] bf16 (pre-scaled by SCALE*LOG2E).
// K stored SLOT-PERMUTED within each 32-token group:
//   token t = 8g+r4 (g=0..3, r4=0..7) -> slot 4g+r4 (r4<4) else 16+4g+(r4-4).
// With this layout, k_attn's two contiguous 16-row K loads put key 8lg+j
// (j=0..7) into lane-group lg's S#1/S#2 regs -> P packs straight into the
// 16x16x32 A-fragment with NO cross-lane ops.
// V written in K=32-B-fragment-major order (same as passing R8):
//   Vf[((bh*128+jb)*2+dhalf)*64 + (js>>3)*16 + (d&15)][js&7]
// ---------------------------------------------------------------------------
__global__ __launch_bounds__(256) void k_qkv(const float* __restrict__ x,
                                             const float* __restrict__ w,
                                             unsigned short* __restrict__ Qb,
                                             unsigned short* __restrict__ Kb,
                                             unsigned short* __restrict__ Vf) {
    __shared__ unsigned short ldsT[64 * 136];
    const int tid = threadIdx.x;
    const int t0 = blockIdx.x * 64;
    const int o0 = blockIdx.y * 64;
    const int b = t0 >> 12;
    const int s0 = t0 & 4095;

    {
        const int t = tid & 63;
        const int cg = (tid >> 6) * 32;
        const float* xp = x + ((size_t)b * 128 + cg) * 4096 + s0 + t;
#pragma unroll
        for (int i = 0; i < 32; ++i)
            ldsT[t * 136 + cg + i] = f2bf(xp[(size_t)i * 4096]);
    }
    __syncthreads();

    const int lane = tid & 63;
    const int wv = tid >> 6;
    const int ln = lane & 15, lg = lane >> 4;
    const int ow = o0 + wv * 16;

    s16x8 aW[4];
#pragma unroll
    for (int ks = 0; ks < 4; ++ks) {
        const float* wp = w + (size_t)(ow + ln) * 128 + ks * 32 + lg * 8;
        s16x8 a;
#pragma unroll
        for (int j = 0; j < 8; ++j) a[j] = (short)f2bf(wp[j]);
        aW[ks] = a;
    }

    f32x4 acc[4] = {{0, 0, 0, 0}, {0, 0, 0, 0}, {0, 0, 0, 0}, {0, 0, 0, 0}};
#pragma unroll
    for (int ts = 0; ts < 4; ++ts) {
#pragma unroll
        for (int ks = 0; ks < 4; ++ks) {
            s16x8 bx = *(const s16x8*)&ldsT[(ts * 16 + ln) * 136 + ks * 32 + lg * 8];
            acc[ts] = MFMA16(aW[ks], bx, acc[ts]);
        }
    }

#pragma unroll
    for (int ts = 0; ts < 4; ++ts) {
        const int s = s0 + ts * 16 + ln;
#pragma unroll
        for (int r = 0; r < 4; ++r) {
            const int o = ow + lg * 4 + r;
            const float v = acc[ts][r];
            if (o < 128) {
                const int h = o >> 5, d = o & 31;
                Qb[((size_t)(b * 4 + h) * 4096 + s) * 32 + d] = f2bf(v * (SCALE * LOG2E));
            } else if (o < 256) {
                const int oo = o - 128, h = oo >> 5, d = oo & 31;
                const int js = s & 31, g = js >> 3, r4 = js & 7;
                const int slot = (r4 < 4) ? (g * 4 + r4) : (16 + g * 4 + (r4 - 4));
                const int sp = (s & ~31) | slot;
                Kb[((size_t)(b * 4 + h) * 4096 + sp) * 32 + d] = f2bf(v);
            } else {
                const int oo = o - 256, h = oo >> 5, d = oo & 31;
                const int bh = b * 4 + h;
                const int jb = s >> 5, js = s & 31;
                const int lanep = (js >> 3) * 16 + (d & 15);
                const size_t idx = ((((size_t)bh * 128 + jb) * 2 + (d >> 4)) * 64 + lanep) * 8 + (js & 7);
                Vf[idx] = f2bf(v);
            }
        }
    }
}

// ---------------------------------------------------------------------------
// K2: fused attention, swapped-QK^T over slot-permuted K.
// S#1 reg r = key 8lg+r, S#2 reg r = key 8lg+4+r  ->  4x cvt_pk builds the
// 16x16x32 PV A-fragment (k=8lg+j) directly. No shfl/cndmask/permlane.
// grid (64 q-tiles of 64, 16 bh), block 512 (8 waves).
// Waves 0-3: keys [0,2048); waves 4-7: keys [2048,4096); same q rows.
// ---------------------------------------------------------------------------
__global__ __launch_bounds__(512) void k_attn(const unsigned short* __restrict__ Qb,
                                              const unsigned short* __restrict__ Kb,
                                              const unsigned short* __restrict__ Vf,
                                              unsigned short* __restrict__ att) {
    __shared__ float comb[4][64][9];  // upper-half waves' partials (9216 B)
    const int tid = threadIdx.x;
    const int lane = tid & 63;
    const int wv = tid >> 6;  // 0..7
    const int ln = lane & 15, lg = lane >> 4;
    const int bh = blockIdx.y;
    const int i0 = blockIdx.x * 64 + (wv & 3) * 16;  // this wave's 16 q rows
    const int khalf = wv >> 2;
    const size_t base = (size_t)bh * 4096 * 32;

    // B-frag Q: lane holds Q[i0+ln][8lg+m]  (pre-scaled by SCALE*LOG2E)
    const s16x8 bQ = *(const s16x8*)(Qb + base + (size_t)(i0 + ln) * 32 + lg * 8);

    const int j0 = khalf * 2048;
    const unsigned short* kp = Kb + base + (size_t)(j0 + ln) * 32 + lg * 8;
    // Vf: [bh][jb][dhalf][lane][t]; this wave starts at jb = khalf*64
    const unsigned short* vp = Vf + (size_t)bh * 131072 + (size_t)(khalf * 64) * 1024 + lane * 8;

    const f32x4 zf = {0.f, 0.f, 0.f, 0.f};
    f32x4 acc0 = zf, acc1 = zf;
    float lsum = 0.f;

    s16x8 K0 = *(const s16x8*)(kp);            // slots 0-15  (keys 8g+0..3)
    s16x8 K1 = *(const s16x8*)(kp + 16 * 32);  // slots 16-31 (keys 8g+4..7)
    s16x8 V0 = *(const s16x8*)(vp);            // d = ln,    tokens 8lg+0..7
    s16x8 V1 = *(const s16x8*)(vp + 512);      // d = 16+ln

    auto body = [&](s16x8 cK0, s16x8 cK1, s16x8 cV0, s16x8 cV1) {
        // S#1: lane(ln,lg) reg r = S[q=i0+ln][key jt + 8lg + r]
        // S#2: lane(ln,lg) reg r = S[q=i0+ln][key jt + 8lg + 4 + r]
        const f32x4 S0 = MFMA16(cK0, bQ, zf);
        const f32x4 S1 = MFMA16(cK1, bQ, zf);
        float p0[4], p1[4];
#pragma unroll
        for (int r = 0; r < 4; ++r) {
            p0[r] = fexp2(S0[r]);
            p1[r] = fexp2(S1[r]);
        }
        lsum += ((p0[0] + p0[1]) + (p0[2] + p0[3])) + ((p1[0] + p1[1]) + (p1[2] + p1[3]));
        // A-frag element j = P[key 8lg+j]: j0-3 from S#1, j4-7 from S#2
        u32x4 apv;
        apv.x = cvtpk(p0[0], p0[1]);
        apv.y = cvtpk(p0[2], p0[3]);
        apv.z = cvtpk(p1[0], p1[1]);
        apv.w = cvtpk(p1[2], p1[3]);
        const s16x8 aP = __builtin_bit_cast(s16x8, apv);
        // PV: D[4lg+r][ln] = out[q=i0+4lg+r][d=ln (acc0) / 16+ln (acc1)]
        acc0 = MFMA16(aP, cV0, acc0);
        acc1 = MFMA16(aP, cV1, acc1);
    };

    for (int it = 0; it < 63; ++it) {
        kp += 32 * 32;
        vp += 1024;
        s16x8 nK0 = *(const s16x8*)(kp);
        s16x8 nK1 = *(const s16x8*)(kp + 16 * 32);
        s16x8 nV0 = *(const s16x8*)(vp);
        s16x8 nV1 = *(const s16x8*)(vp + 512);
        body(K0, K1, V0, V1);
        K0 = nK0; K1 = nK1; V0 = nV0; V1 = nV1;
    }
    body(K0, K1, V0, V1);

    // ---- combine the two K-halves ----
    if (wv >= 4) {
        float* p = &comb[wv - 4][lane][0];
        p[0] = acc0[0]; p[1] = acc0[1]; p[2] = acc0[2]; p[3] = acc0[3];
        p[4] = acc1[0]; p[5] = acc1[1]; p[6] = acc1[2]; p[7] = acc1[3];
        p[8] = lsum;
    }
    __syncthreads();
    if (wv < 4) {
        const float* p = &comb[wv][lane][0];
        acc0[0] += p[0]; acc0[1] += p[1]; acc0[2] += p[2]; acc0[3] += p[3];
        acc1[0] += p[4]; acc1[1] += p[5]; acc1[2] += p[6]; acc1[3] += p[7];
        lsum += p[8];
        // full row sums: reduce over lg groups -> every lane has total for q=i0+ln
        lsum += __shfl_xor(lsum, 16);
        lsum += __shfl_xor(lsum, 32);
        const int b = bh >> 2, h = bh & 3;
#pragma unroll
        for (int r = 0; r < 4; ++r) {
            const float rs = __shfl(lsum, 4 * lg + r);  // sum for q row 4lg+r
            const float rinv = 1.0f / rs;
            const int q = i0 + lg * 4 + r;
            const size_t rowoff = ((size_t)b * 4096 + q) * 128 + h * 32;
            att[rowoff + ln] = f2bf(acc0[r] * rinv);
            att[rowoff + 16 + ln] = f2bf(acc1[r] * rinv);
        }
    }
}

// ---------------------------------------------------------------------------
// K3: out projection (unchanged).
// ---------------------------------------------------------------------------
__global__ __launch_bounds__(256) void k_out(const unsigned short* __restrict__ att,
                                             const float* __restrict__ w,
                                             const float* __restrict__ bias,
                                             float* __restrict__ out) {
    const int tid = threadIdx.x;
    const int lane = tid & 63;
    const int wv = tid >> 6;
    const int ln = lane & 15, lg = lane >> 4;
    const int t0 = blockIdx.x * 64;
    const int o0 = blockIdx.y * 64;
    const int ow = o0 + wv * 16;
    const int b = t0 >> 12, s0 = t0 & 4095;

    s16x8 aW[4];
#pragma unroll
    for (int ks = 0; ks < 4; ++ks) {
        const float* wp = w + (size_t)(ow + ln) * 128 + ks * 32 + lg * 8;
        s16x8 a;
#pragma unroll
        for (int j = 0; j < 8; ++j) a[j] = (short)f2bf(wp[j]);
        aW[ks] = a;
    }

    f32x4 acc[4] = {{0, 0, 0, 0}, {0, 0, 0, 0}, {0, 0, 0, 0}, {0, 0, 0, 0}};
#pragma unroll
    for (int ts = 0; ts < 4; ++ts) {
#pragma unroll
        for (int ks = 0; ks < 4; ++ks) {
            s16x8 bx = *(const s16x8*)(att + ((size_t)t0 + ts * 16 + ln) * 128 + ks * 32 + lg * 8);
            acc[ts] = MFMA16(aW[ks], bx, acc[ts]);
        }
    }

#pragma unroll
    for (int ts = 0; ts < 4; ++ts) {
        const int s = s0 + ts * 16 + ln;
#pragma unroll
        for (int r = 0; r < 4; ++r) {
            const int o = ow + lg * 4 + r;
            out[((size_t)b * 128 + o) * 4096 + s] = acc[ts][r] + bias[o];
        }
    }
}

// ---------------------------------------------------------------------------
extern "C" void kernel_launch(void* const* d_in, const int* in_sizes, int n_in,
                              void* d_out, int out_size, void* d_ws, size_t ws_size,
                              hipStream_t stream) {
    const float* x = (const float*)d_in[0];
    const float* w_qkv = (const float*)d_in[1];
    const float* w_out = (const float*)d_in[2];
    const float* b_out = (const float*)d_in[3];
    float* out = (float*)d_out;

    unsigned short* Qb = (unsigned short*)d_ws;               // 4 MiB
    unsigned short* Kb = Qb + (size_t)16 * 4096 * 32;         // 4 MiB (slot-permuted)
    unsigned short* Vf = Kb + (size_t)16 * 4096 * 32;         // 4 MiB (fragment-major)
    unsigned short* att = Vf + (size_t)16 * 4096 * 32;        // 4 MiB

    k_qkv<<<dim3(256, 6), 256, 0, stream>>>(x, w_qkv, Qb, Kb, Vf);
    k_attn<<<dim3(64, 16), 512, 0, stream>>>(Qb, Kb, Vf, att);
    k_out<<<dim3(256, 2), 256, 0, stream>>>(att, w_out, b_out, out);
}

// Round 11
// 78.990 us; speedup vs baseline: 2.5605x; 1.5180x over previous
//
#include <hip/hip_runtime.h>

typedef float f32x4 __attribute__((ext_vector_type(4)));
typedef short s16x8 __attribute__((ext_vector_type(8)));
typedef unsigned int u32;
typedef unsigned int u32x4 __attribute__((ext_vector_type(4)));

#define SCALE 0.17677669529663687f
#define LOG2E 1.4426950408889634f

__device__ __forceinline__ unsigned short f2bf(float f) {
    unsigned u = __builtin_bit_cast(unsigned, f);
    u += 0x7fffu + ((u >> 16) & 1u);
    return (unsigned short)(u >> 16);
}

__device__ __forceinline__ float fexp2(float x) {
#if __has_builtin(__builtin_amdgcn_exp2f)
    return __builtin_amdgcn_exp2f(x);
#else
    return exp2f(x);
#endif
}

// packed f32 pair -> bf16x2 (RNE), dst.lo = lo
__device__ __forceinline__ u32 cvtpk(float lo, float hi) {
    u32 r;
    asm("v_cvt_pk_bf16_f32 %0, %1, %2" : "=v"(r) : "v"(lo), "v"(hi));
    return r;
}

#define MFMA16(a, b, c) __builtin_amdgcn_mfma_f32_16x16x32_bf16((a), (b), (c), 0, 0, 0)

// ---------------------------------------------------------------------------
// K1: qkv projection (byte-identical to passing R10).
// Q as [bh][tok][32] bf16 (pre-scaled by SCALE*LOG2E).
// K slot-permuted within each 32-token group (t=8g+r4 -> 4g+r4 / 16+4g+r4-4)
// so contiguous K loads put key 8lg+j into the right regs for direct A-frag pack.
// V in K=32-B-fragment-major order.
// ---------------------------------------------------------------------------
__global__ __launch_bounds__(256) void k_qkv(const float* __restrict__ x,
                                             const float* __restrict__ w,
                                             unsigned short* __restrict__ Qb,
                                             unsigned short* __restrict__ Kb,
                                             unsigned short* __restrict__ Vf) {
    __shared__ unsigned short ldsT[64 * 136];
    const int tid = threadIdx.x;
    const int t0 = blockIdx.x * 64;
    const int o0 = blockIdx.y * 64;
    const int b = t0 >> 12;
    const int s0 = t0 & 4095;

    {
        const int t = tid & 63;
        const int cg = (tid >> 6) * 32;
        const float* xp = x + ((size_t)b * 128 + cg) * 4096 + s0 + t;
#pragma unroll
        for (int i = 0; i < 32; ++i)
            ldsT[t * 136 + cg + i] = f2bf(xp[(size_t)i * 4096]);
    }
    __syncthreads();

    const int lane = tid & 63;
    const int wv = tid >> 6;
    const int ln = lane & 15, lg = lane >> 4;
    const int ow = o0 + wv * 16;

    s16x8 aW[4];
#pragma unroll
    for (int ks = 0; ks < 4; ++ks) {
        const float* wp = w + (size_t)(ow + ln) * 128 + ks * 32 + lg * 8;
        s16x8 a;
#pragma unroll
        for (int j = 0; j < 8; ++j) a[j] = (short)f2bf(wp[j]);
        aW[ks] = a;
    }

    f32x4 acc[4] = {{0, 0, 0, 0}, {0, 0, 0, 0}, {0, 0, 0, 0}, {0, 0, 0, 0}};
#pragma unroll
    for (int ts = 0; ts < 4; ++ts) {
#pragma unroll
        for (int ks = 0; ks < 4; ++ks) {
            s16x8 bx = *(const s16x8*)&ldsT[(ts * 16 + ln) * 136 + ks * 32 + lg * 8];
            acc[ts] = MFMA16(aW[ks], bx, acc[ts]);
        }
    }

#pragma unroll
    for (int ts = 0; ts < 4; ++ts) {
        const int s = s0 + ts * 16 + ln;
#pragma unroll
        for (int r = 0; r < 4; ++r) {
            const int o = ow + lg * 4 + r;
            const float v = acc[ts][r];
            if (o < 128) {
                const int h = o >> 5, d = o & 31;
                Qb[((size_t)(b * 4 + h) * 4096 + s) * 32 + d] = f2bf(v * (SCALE * LOG2E));
            } else if (o < 256) {
                const int oo = o - 128, h = oo >> 5, d = oo & 31;
                const int js = s & 31, g = js >> 3, r4 = js & 7;
                const int slot = (r4 < 4) ? (g * 4 + r4) : (16 + g * 4 + (r4 - 4));
                const int sp = (s & ~31) | slot;
                Kb[((size_t)(b * 4 + h) * 4096 + sp) * 32 + d] = f2bf(v);
            } else {
                const int oo = o - 256, h = oo >> 5, d = oo & 31;
                const int bh = b * 4 + h;
                const int jb = s >> 5, js = s & 31;
                const int lanep = (js >> 3) * 16 + (d & 15);
                const size_t idx = ((((size_t)bh * 128 + jb) * 2 + (d >> 4)) * 64 + lanep) * 8 + (js & 7);
                Vf[idx] = f2bf(v);
            }
        }
    }
}

// ---------------------------------------------------------------------------
// K2: fused attention. R10 structure, but 32 q-rows per wave (two Q B-frags
// sharing each K/V load) -> halves total L2 K/V traffic (2.1GB -> 1.05GB).
// grid (32 q-tiles of 128, 16 bh), block 512 (8 waves).
// wv&3 -> q-subtile (32 rows), wv>>2 -> K-half. Combine via LDS at the end.
// ---------------------------------------------------------------------------
__global__ __launch_bounds__(512) void k_attn(const unsigned short* __restrict__ Qb,
                                              const unsigned short* __restrict__ Kb,
                                              const unsigned short* __restrict__ Vf,
                                              unsigned short* __restrict__ att) {
    __shared__ float comb[4][64][18];  // upper-half waves' partials (18432 B)
    const int tid = threadIdx.x;
    const int lane = tid & 63;
    const int wv = tid >> 6;  // 0..7
    const int ln = lane & 15, lg = lane >> 4;
    const int bh = blockIdx.y;
    const int i0 = blockIdx.x * 128 + (wv & 3) * 32;  // this wave's 32 q rows
    const int khalf = wv >> 2;
    const size_t base = (size_t)bh * 4096 * 32;

    // B-frags Q: rows i0+ln (qs=0) and i0+16+ln (qs=1), k = 8lg+m
    const s16x8 bQ0 = *(const s16x8*)(Qb + base + (size_t)(i0 + ln) * 32 + lg * 8);
    const s16x8 bQ1 = *(const s16x8*)(Qb + base + (size_t)(i0 + 16 + ln) * 32 + lg * 8);

    const int j0 = khalf * 2048;
    const unsigned short* kp = Kb + base + (size_t)(j0 + ln) * 32 + lg * 8;
    const unsigned short* vp = Vf + (size_t)bh * 131072 + (size_t)(khalf * 64) * 1024 + lane * 8;

    const f32x4 zf = {0.f, 0.f, 0.f, 0.f};
    f32x4 acc00 = zf, acc01 = zf, acc10 = zf, acc11 = zf;  // [qs][dhalf]
    float lsum0 = 0.f, lsum1 = 0.f;

    s16x8 K0 = *(const s16x8*)(kp);            // slots 0-15  (keys 8g+0..3)
    s16x8 K1 = *(const s16x8*)(kp + 16 * 32);  // slots 16-31 (keys 8g+4..7)
    s16x8 V0 = *(const s16x8*)(vp);            // d = ln
    s16x8 V1 = *(const s16x8*)(vp + 512);      // d = 16+ln

    auto body = [&](s16x8 cK0, s16x8 cK1, s16x8 cV0, s16x8 cV1) {
        // S[qs][f]: lane(ln,lg) reg r = S[q=i0+16qs+ln][key jt + 8lg + 4f + r]
        const f32x4 S00 = MFMA16(cK0, bQ0, zf);
        const f32x4 S01 = MFMA16(cK1, bQ0, zf);
        const f32x4 S10 = MFMA16(cK0, bQ1, zf);
        const f32x4 S11 = MFMA16(cK1, bQ1, zf);
        float p00[4], p01[4], p10[4], p11[4];
#pragma unroll
        for (int r = 0; r < 4; ++r) {
            p00[r] = fexp2(S00[r]);
            p01[r] = fexp2(S01[r]);
            p10[r] = fexp2(S10[r]);
            p11[r] = fexp2(S11[r]);
        }
        lsum0 += ((p00[0] + p00[1]) + (p00[2] + p00[3])) + ((p01[0] + p01[1]) + (p01[2] + p01[3]));
        lsum1 += ((p10[0] + p10[1]) + (p10[2] + p10[3])) + ((p11[0] + p11[1]) + (p11[2] + p11[3]));
        // A-frag element j = P[key 8lg+j]: j0-3 from S*0, j4-7 from S*1
        u32x4 a0, a1;
        a0.x = cvtpk(p00[0], p00[1]);
        a0.y = cvtpk(p00[2], p00[3]);
        a0.z = cvtpk(p01[0], p01[1]);
        a0.w = cvtpk(p01[2], p01[3]);
        a1.x = cvtpk(p10[0], p10[1]);
        a1.y = cvtpk(p10[2], p10[3]);
        a1.z = cvtpk(p11[0], p11[1]);
        a1.w = cvtpk(p11[2], p11[3]);
        const s16x8 aP0 = __builtin_bit_cast(s16x8, a0);
        const s16x8 aP1 = __builtin_bit_cast(s16x8, a1);
        // PV: D[4lg+r][ln] = out[q=i0+16qs+4lg+r][d=ln / 16+ln]
        acc00 = MFMA16(aP0, cV0, acc00);
        acc01 = MFMA16(aP0, cV1, acc01);
        acc10 = MFMA16(aP1, cV0, acc10);
        acc11 = MFMA16(aP1, cV1, acc11);
    };

    for (int it = 0; it < 63; ++it) {
        kp += 32 * 32;
        vp += 1024;
        s16x8 nK0 = *(const s16x8*)(kp);
        s16x8 nK1 = *(const s16x8*)(kp + 16 * 32);
        s16x8 nV0 = *(const s16x8*)(vp);
        s16x8 nV1 = *(const s16x8*)(vp + 512);
        body(K0, K1, V0, V1);
        K0 = nK0; K1 = nK1; V0 = nV0; V1 = nV1;
    }
    body(K0, K1, V0, V1);

    // ---- combine the two K-halves ----
    if (wv >= 4) {
        float* p = &comb[wv - 4][lane][0];
        p[0] = acc00[0]; p[1] = acc00[1]; p[2] = acc00[2]; p[3] = acc00[3];
        p[4] = acc01[0]; p[5] = acc01[1]; p[6] = acc01[2]; p[7] = acc01[3];
        p[8] = lsum0;
        p[9] = acc10[0]; p[10] = acc10[1]; p[11] = acc10[2]; p[12] = acc10[3];
        p[13] = acc11[0]; p[14] = acc11[1]; p[15] = acc11[2]; p[16] = acc11[3];
        p[17] = lsum1;
    }
    __syncthreads();
    if (wv < 4) {
        const float* p = &comb[wv][lane][0];
        acc00[0] += p[0]; acc00[1] += p[1]; acc00[2] += p[2]; acc00[3] += p[3];
        acc01[0] += p[4]; acc01[1] += p[5]; acc01[2] += p[6]; acc01[3] += p[7];
        lsum0 += p[8];
        acc10[0] += p[9]; acc10[1] += p[10]; acc10[2] += p[11]; acc10[3] += p[12];
        acc11[0] += p[13]; acc11[1] += p[14]; acc11[2] += p[15]; acc11[3] += p[16];
        lsum1 += p[17];
        // full row sums across lg groups; lane ln then holds total for its q-row
        lsum0 += __shfl_xor(lsum0, 16);
        lsum0 += __shfl_xor(lsum0, 32);
        lsum1 += __shfl_xor(lsum1, 16);
        lsum1 += __shfl_xor(lsum1, 32);
        const int b = bh >> 2, h = bh & 3;
#pragma unroll
        for (int r = 0; r < 4; ++r) {
            const float rs0 = __shfl(lsum0, 4 * lg + r);  // q row 4lg+r (qs=0)
            const float rs1 = __shfl(lsum1, 4 * lg + r);  // q row 4lg+r (qs=1)
            const float ri0 = 1.0f / rs0;
            const float ri1 = 1.0f / rs1;
            const int q0 = i0 + lg * 4 + r;
            const int q1 = i0 + 16 + lg * 4 + r;
            const size_t off0 = ((size_t)b * 4096 + q0) * 128 + h * 32;
            const size_t off1 = ((size_t)b * 4096 + q1) * 128 + h * 32;
            att[off0 + ln] = f2bf(acc00[r] * ri0);
            att[off0 + 16 + ln] = f2bf(acc01[r] * ri0);
            att[off1 + ln] = f2bf(acc10[r] * ri1);
            att[off1 + 16 + ln] = f2bf(acc11[r] * ri1);
        }
    }
}

// ---------------------------------------------------------------------------
// K3: out projection (unchanged).
// ---------------------------------------------------------------------------
__global__ __launch_bounds__(256) void k_out(const unsigned short* __restrict__ att,
                                             const float* __restrict__ w,
                                             const float* __restrict__ bias,
                                             float* __restrict__ out) {
    const int tid = threadIdx.x;
    const int lane = tid & 63;
    const int wv = tid >> 6;
    const int ln = lane & 15, lg = lane >> 4;
    const int t0 = blockIdx.x * 64;
    const int o0 = blockIdx.y * 64;
    const int ow = o0 + wv * 16;
    const int b = t0 >> 12, s0 = t0 & 4095;

    s16x8 aW[4];
#pragma unroll
    for (int ks = 0; ks < 4; ++ks) {
        const float* wp = w + (size_t)(ow + ln) * 128 + ks * 32 + lg * 8;
        s16x8 a;
#pragma unroll
        for (int j = 0; j < 8; ++j) a[j] = (short)f2bf(wp[j]);
        aW[ks] = a;
    }

    f32x4 acc[4] = {{0, 0, 0, 0}, {0, 0, 0, 0}, {0, 0, 0, 0}, {0, 0, 0, 0}};
#pragma unroll
    for (int ts = 0; ts < 4; ++ts) {
#pragma unroll
        for (int ks = 0; ks < 4; ++ks) {
            s16x8 bx = *(const s16x8*)(att + ((size_t)t0 + ts * 16 + ln) * 128 + ks * 32 + lg * 8);
            acc[ts] = MFMA16(aW[ks], bx, acc[ts]);
        }
    }

#pragma unroll
    for (int ts = 0; ts < 4; ++ts) {
        const int s = s0 + ts * 16 + ln;
#pragma unroll
        for (int r = 0; r < 4; ++r) {
            const int o = ow + lg * 4 + r;
            out[((size_t)b * 128 + o) * 4096 + s] = acc[ts][r] + bias[o];
        }
    }
}

// ---------------------------------------------------------------------------
extern "C" void kernel_launch(void* const* d_in, const int* in_sizes, int n_in,
                              void* d_out, int out_size, void* d_ws, size_t ws_size,
                              hipStream_t stream) {
    const float* x = (const float*)d_in[0];
    const float* w_qkv = (const float*)d_in[1];
    const float* w_out = (const float*)d_in[2];
    const float* b_out = (const float*)d_in[3];
    float* out = (float*)d_out;

    unsigned short* Qb = (unsigned short*)d_ws;               // 4 MiB
    unsigned short* Kb = Qb + (size_t)16 * 4096 * 32;         // 4 MiB (slot-permuted)
    unsigned short* Vf = Kb + (size_t)16 * 4096 * 32;         // 4 MiB (fragment-major)
    unsigned short* att = Vf + (size_t)16 * 4096 * 32;        // 4 MiB

    k_qkv<<<dim3(256, 6), 256, 0, stream>>>(x, w_qkv, Qb, Kb, Vf);
    k_attn<<<dim3(32, 16), 512, 0, stream>>>(Qb, Kb, Vf, att);
    k_out<<<dim3(256, 2), 256, 0, stream>>>(att, w_out, b_out, out);
}

// Round 13
// 76.292 us; speedup vs baseline: 2.6511x; 1.0354x over previous
//
#include <hip/hip_runtime.h>

typedef float f32x4 __attribute__((ext_vector_type(4)));
typedef short s16x8 __attribute__((ext_vector_type(8)));
typedef unsigned int u32;
typedef unsigned int u32x4 __attribute__((ext_vector_type(4)));

#define SCALE 0.17677669529663687f
#define LOG2E 1.4426950408889634f

__device__ __forceinline__ unsigned short f2bf(float f) {
    unsigned u = __builtin_bit_cast(unsigned, f);
    u += 0x7fffu + ((u >> 16) & 1u);
    return (unsigned short)(u >> 16);
}

__device__ __forceinline__ float fexp2(float x) {
#if __has_builtin(__builtin_amdgcn_exp2f)
    return __builtin_amdgcn_exp2f(x);
#else
    return exp2f(x);
#endif
}

// packed f32 pair -> bf16x2 (RNE), dst.lo = lo
__device__ __forceinline__ u32 cvtpk(float lo, float hi) {
    u32 r;
    asm("v_cvt_pk_bf16_f32 %0, %1, %2" : "=v"(r) : "v"(lo), "v"(hi));
    return r;
}

#define MFMA16(a, b, c) __builtin_amdgcn_mfma_f32_16x16x32_bf16((a), (b), (c), 0, 0, 0)

// ---------------------------------------------------------------------------
// K1: qkv projection (byte-identical to passing R10/R11).
// Q as [bh][tok][32] bf16 (pre-scaled by SCALE*LOG2E).
// K slot-permuted within each 32-token group (t=8g+r4 -> 4g+r4 / 16+4g+r4-4)
// so contiguous K loads put key 8lg+j into the right regs for direct A-frag pack.
// V in K=32-B-fragment-major order.
// ---------------------------------------------------------------------------
__global__ __launch_bounds__(256) void k_qkv(const float* __restrict__ x,
                                             const float* __restrict__ w,
                                             unsigned short* __restrict__ Qb,
                                             unsigned short* __restrict__ Kb,
                                             unsigned short* __restrict__ Vf) {
    __shared__ unsigned short ldsT[64 * 136];
    const int tid = threadIdx.x;
    const int t0 = blockIdx.x * 64;
    const int o0 = blockIdx.y * 64;
    const int b = t0 >> 12;
    const int s0 = t0 & 4095;

    {
        const int t = tid & 63;
        const int cg = (tid >> 6) * 32;
        const float* xp = x + ((size_t)b * 128 + cg) * 4096 + s0 + t;
#pragma unroll
        for (int i = 0; i < 32; ++i)
            ldsT[t * 136 + cg + i] = f2bf(xp[(size_t)i * 4096]);
    }
    __syncthreads();

    const int lane = tid & 63;
    const int wv = tid >> 6;
    const int ln = lane & 15, lg = lane >> 4;
    const int ow = o0 + wv * 16;

    s16x8 aW[4];
#pragma unroll
    for (int ks = 0; ks < 4; ++ks) {
        const float* wp = w + (size_t)(ow + ln) * 128 + ks * 32 + lg * 8;
        s16x8 a;
#pragma unroll
        for (int j = 0; j < 8; ++j) a[j] = (short)f2bf(wp[j]);
        aW[ks] = a;
    }

    f32x4 acc[4] = {{0, 0, 0, 0}, {0, 0, 0, 0}, {0, 0, 0, 0}, {0, 0, 0, 0}};
#pragma unroll
    for (int ts = 0; ts < 4; ++ts) {
#pragma unroll
        for (int ks = 0; ks < 4; ++ks) {
            s16x8 bx = *(const s16x8*)&ldsT[(ts * 16 + ln) * 136 + ks * 32 + lg * 8];
            acc[ts] = MFMA16(aW[ks], bx, acc[ts]);
        }
    }

#pragma unroll
    for (int ts = 0; ts < 4; ++ts) {
        const int s = s0 + ts * 16 + ln;
#pragma unroll
        for (int r = 0; r < 4; ++r) {
            const int o = ow + lg * 4 + r;
            const float v = acc[ts][r];
            if (o < 128) {
                const int h = o >> 5, d = o & 31;
                Qb[((size_t)(b * 4 + h) * 4096 + s) * 32 + d] = f2bf(v * (SCALE * LOG2E));
            } else if (o < 256) {
                const int oo = o - 128, h = oo >> 5, d = oo & 31;
                const int js = s & 31, g = js >> 3, r4 = js & 7;
                const int slot = (r4 < 4) ? (g * 4 + r4) : (16 + g * 4 + (r4 - 4));
                const int sp = (s & ~31) | slot;
                Kb[((size_t)(b * 4 + h) * 4096 + sp) * 32 + d] = f2bf(v);
            } else {
                const int oo = o - 256, h = oo >> 5, d = oo & 31;
                const int bh = b * 4 + h;
                const int jb = s >> 5, js = s & 31;
                const int lanep = (js >> 3) * 16 + (d & 15);
                const size_t idx = ((((size_t)bh * 128 + jb) * 2 + (d >> 4)) * 64 + lanep) * 8 + (js & 7);
                Vf[idx] = f2bf(v);
            }
        }
    }
}

// ---------------------------------------------------------------------------
// K2: fused attention with block-shared LDS K/V staging.
// grid (16 q-tiles of 256, 16 bh), block 512 (8 waves x 32 q-rows, NO K split).
// 32 tiles of 128 keys; each tile is a CONTIGUOUS 8KB span of both Kb and Vf
// (layouts were built for this), so staging = linear copy (tid*16B), and all
// body ds_reads are linear/conflict-free. Double-buffered, one barrier/tile,
// next tile's global loads issued one tile ahead (latency hidden under compute).
// Body math identical to R11. No cross-wave combine needed.
// ---------------------------------------------------------------------------
__global__ __launch_bounds__(512) void k_attn(const unsigned short* __restrict__ Qb,
                                              const unsigned short* __restrict__ Kb,
                                              const unsigned short* __restrict__ Vf,
                                              unsigned short* __restrict__ att) {
    __shared__ __align__(16) char lds[2][16384];  // per buf: K 8KB | V 8KB
    const int tid = threadIdx.x;
    const int lane = tid & 63;
    const int wv = tid >> 6;  // 0..7
    const int ln = lane & 15, lg = lane >> 4;
    const int bh = blockIdx.y;
    const int i0 = blockIdx.x * 256 + wv * 32;  // this wave's 32 q rows
    const size_t base = (size_t)bh * 4096 * 32;

    // B-frags Q: rows i0+ln (qs=0) and i0+16+ln (qs=1), k = 8lg+m
    const s16x8 bQ0 = *(const s16x8*)(Qb + base + (size_t)(i0 + ln) * 32 + lg * 8);
    const s16x8 bQ1 = *(const s16x8*)(Qb + base + (size_t)(i0 + 16 + ln) * 32 + lg * 8);

    // global tile sources (each 128-key tile = contiguous 8KB in both arrays)
    const char* gK = (const char*)Kb + base * 2;  // bh*262144 bytes
    const char* gV = (const char*)Vf + (size_t)bh * 262144;

    const f32x4 zf = {0.f, 0.f, 0.f, 0.f};
    f32x4 acc00 = zf, acc01 = zf, acc10 = zf, acc11 = zf;  // [qs][dhalf]
    float lsum0 = 0.f, lsum1 = 0.f;

    auto body = [&](s16x8 cK0, s16x8 cK1, s16x8 cV0, s16x8 cV1) {
        const f32x4 S00 = MFMA16(cK0, bQ0, zf);
        const f32x4 S01 = MFMA16(cK1, bQ0, zf);
        const f32x4 S10 = MFMA16(cK0, bQ1, zf);
        const f32x4 S11 = MFMA16(cK1, bQ1, zf);
        float p00[4], p01[4], p10[4], p11[4];
#pragma unroll
        for (int r = 0; r < 4; ++r) {
            p00[r] = fexp2(S00[r]);
            p01[r] = fexp2(S01[r]);
            p10[r] = fexp2(S10[r]);
            p11[r] = fexp2(S11[r]);
        }
        lsum0 += ((p00[0] + p00[1]) + (p00[2] + p00[3])) + ((p01[0] + p01[1]) + (p01[2] + p01[3]));
        lsum1 += ((p10[0] + p10[1]) + (p10[2] + p10[3])) + ((p11[0] + p11[1]) + (p11[2] + p11[3]));
        u32x4 a0, a1;
        a0.x = cvtpk(p00[0], p00[1]);
        a0.y = cvtpk(p00[2], p00[3]);
        a0.z = cvtpk(p01[0], p01[1]);
        a0.w = cvtpk(p01[2], p01[3]);
        a1.x = cvtpk(p10[0], p10[1]);
        a1.y = cvtpk(p10[2], p10[3]);
        a1.z = cvtpk(p11[0], p11[1]);
        a1.w = cvtpk(p11[2], p11[3]);
        const s16x8 aP0 = __builtin_bit_cast(s16x8, a0);
        const s16x8 aP1 = __builtin_bit_cast(s16x8, a1);
        acc00 = MFMA16(aP0, cV0, acc00);
        acc01 = MFMA16(aP0, cV1, acc01);
        acc10 = MFMA16(aP1, cV0, acc10);
        acc11 = MFMA16(aP1, cV1, acc11);
    };

    // compute 4 x 32-key groups from LDS buffer `buf`
    auto COMPUTE = [&](int buf) {
        const char* kb = lds[buf];
        const char* vb = lds[buf] + 8192;
#pragma unroll
        for (int ii = 0; ii < 4; ++ii) {
            const s16x8 cK0 = *(const s16x8*)(kb + ii * 2048 + ln * 64 + lg * 16);
            const s16x8 cK1 = *(const s16x8*)(kb + ii * 2048 + 1024 + ln * 64 + lg * 16);
            const s16x8 cV0 = *(const s16x8*)(vb + ii * 2048 + lane * 16);
            const s16x8 cV1 = *(const s16x8*)(vb + ii * 2048 + 1024 + lane * 16);
            body(cK0, cK1, cV0, cV1);
        }
    };

    // ---- staged main loop: 32 tiles of 128 keys ----
    s16x8 kr = *(const s16x8*)(gK + tid * 16);
    s16x8 vr = *(const s16x8*)(gV + tid * 16);
    *(s16x8*)(lds[0] + tid * 16) = kr;
    *(s16x8*)(lds[0] + 8192 + tid * 16) = vr;
    __syncthreads();
    kr = *(const s16x8*)(gK + 8192 + tid * 16);  // tile 1 in flight
    vr = *(const s16x8*)(gV + 8192 + tid * 16);

    for (int t = 0; t < 32; ++t) {
        COMPUTE(t & 1);
        if (t < 31) {
            *(s16x8*)(lds[(t + 1) & 1] + tid * 16) = kr;
            *(s16x8*)(lds[(t + 1) & 1] + 8192 + tid * 16) = vr;
            if (t < 30) {
                kr = *(const s16x8*)(gK + (size_t)(t + 2) * 8192 + tid * 16);
                vr = *(const s16x8*)(gV + (size_t)(t + 2) * 8192 + tid * 16);
            }
        }
        __syncthreads();
    }

    // ---- epilogue: full row sums in-wave (no cross-wave combine) ----
    lsum0 += __shfl_xor(lsum0, 16);
    lsum0 += __shfl_xor(lsum0, 32);
    lsum1 += __shfl_xor(lsum1, 16);
    lsum1 += __shfl_xor(lsum1, 32);
    const int b = bh >> 2, h = bh & 3;
#pragma unroll
    for (int r = 0; r < 4; ++r) {
        const float rs0 = __shfl(lsum0, 4 * lg + r);  // q row 4lg+r (qs=0)
        const float rs1 = __shfl(lsum1, 4 * lg + r);  // q row 4lg+r (qs=1)
        const float ri0 = 1.0f / rs0;
        const float ri1 = 1.0f / rs1;
        const int q0 = i0 + lg * 4 + r;
        const int q1 = i0 + 16 + lg * 4 + r;
        const size_t off0 = ((size_t)b * 4096 + q0) * 128 + h * 32;
        const size_t off1 = ((size_t)b * 4096 + q1) * 128 + h * 32;
        att[off0 + ln] = f2bf(acc00[r] * ri0);
        att[off0 + 16 + ln] = f2bf(acc01[r] * ri0);
        att[off1 + ln] = f2bf(acc10[r] * ri1);
        att[off1 + 16 + ln] = f2bf(acc11[r] * ri1);
    }
}

// ---------------------------------------------------------------------------
// K3: out projection (unchanged).
// ---------------------------------------------------------------------------
__global__ __launch_bounds__(256) void k_out(const unsigned short* __restrict__ att,
                                             const float* __restrict__ w,
                                             const float* __restrict__ bias,
                                             float* __restrict__ out) {
    const int tid = threadIdx.x;
    const int lane = tid & 63;
    const int wv = tid >> 6;
    const int ln = lane & 15, lg = lane >> 4;
    const int t0 = blockIdx.x * 64;
    const int o0 = blockIdx.y * 64;
    const int ow = o0 + wv * 16;
    const int b = t0 >> 12, s0 = t0 & 4095;

    s16x8 aW[4];
#pragma unroll
    for (int ks = 0; ks < 4; ++ks) {
        const float* wp = w + (size_t)(ow + ln) * 128 + ks * 32 + lg * 8;
        s16x8 a;
#pragma unroll
        for (int j = 0; j < 8; ++j) a[j] = (short)f2bf(wp[j]);
        aW[ks] = a;
    }

    f32x4 acc[4] = {{0, 0, 0, 0}, {0, 0, 0, 0}, {0, 0, 0, 0}, {0, 0, 0, 0}};
#pragma unroll
    for (int ts = 0; ts < 4; ++ts) {
#pragma unroll
        for (int ks = 0; ks < 4; ++ks) {
            s16x8 bx = *(const s16x8*)(att + ((size_t)t0 + ts * 16 + ln) * 128 + ks * 32 + lg * 8);
            acc[ts] = MFMA16(aW[ks], bx, acc[ts]);
        }
    }

#pragma unroll
    for (int ts = 0; ts < 4; ++ts) {
        const int s = s0 + ts * 16 + ln;
#pragma unroll
        for (int r = 0; r < 4; ++r) {
            const int o = ow + lg * 4 + r;
            out[((size_t)b * 128 + o) * 4096 + s] = acc[ts][r] + bias[o];
        }
    }
}

// ---------------------------------------------------------------------------
extern "C" void kernel_launch(void* const* d_in, const int* in_sizes, int n_in,
                              void* d_out, int out_size, void* d_ws, size_t ws_size,
                              hipStream_t stream) {
    const float* x = (const float*)d_in[0];
    const float* w_qkv = (const float*)d_in[1];
    const float* w_out = (const float*)d_in[2];
    const float* b_out = (const float*)d_in[3];
    float* out = (float*)d_out;

    unsigned short* Qb = (unsigned short*)d_ws;               // 4 MiB
    unsigned short* Kb = Qb + (size_t)16 * 4096 * 32;         // 4 MiB (slot-permuted)
    unsigned short* Vf = Kb + (size_t)16 * 4096 * 32;         // 4 MiB (fragment-major)
    unsigned short* att = Vf + (size_t)16 * 4096 * 32;        // 4 MiB

    k_qkv<<<dim3(256, 6), 256, 0, stream>>>(x, w_qkv, Qb, Kb, Vf);
    k_attn<<<dim3(16, 16), 512, 0, stream>>>(Qb, Kb, Vf, att);
    k_out<<<dim3(256, 2), 256, 0, stream>>>(att, w_out, b_out, out);
}

// Round 15
// 75.728 us; speedup vs baseline: 2.6708x; 1.0074x over previous
//
#include <hip/hip_runtime.h>

typedef float f32x4 __attribute__((ext_vector_type(4)));
typedef short s16x8 __attribute__((ext_vector_type(8)));
typedef unsigned int u32;
typedef unsigned int u32x4 __attribute__((ext_vector_type(4)));

#define SCALE 0.17677669529663687f
#define LOG2E 1.4426950408889634f

__device__ __forceinline__ unsigned short f2bf(float f) {
    unsigned u = __builtin_bit_cast(unsigned, f);
    u += 0x7fffu + ((u >> 16) & 1u);
    return (unsigned short)(u >> 16);
}

__device__ __forceinline__ float fexp2(float x) {
#if __has_builtin(__builtin_amdgcn_exp2f)
    return __builtin_amdgcn_exp2f(x);
#else
    return exp2f(x);
#endif
}

// packed f32 pair -> bf16x2 (RNE), dst.lo = lo
__device__ __forceinline__ u32 cvtpk(float lo, float hi) {
    u32 r;
    asm("v_cvt_pk_bf16_f32 %0, %1, %2" : "=v"(r) : "v"(lo), "v"(hi));
    return r;
}

#define MFMA16(a, b, c) __builtin_amdgcn_mfma_f32_16x16x32_bf16((a), (b), (c), 0, 0, 0)

// ---------------------------------------------------------------------------
// K1: qkv projection. THIS ROUND: grid 256 (no y); each block stages its
// 64-token x-tile ONCE and loops all 6 o-tiles (os) -> x read 48MB -> 8MB.
// Inner MFMA + epilogue code identical to passing R13.
// Q as [bh][tok][32] bf16 (pre-scaled by SCALE*LOG2E).
// K slot-permuted within each 32-token group; V fragment-major (unchanged).
// ---------------------------------------------------------------------------
__global__ __launch_bounds__(256) void k_qkv(const float* __restrict__ x,
                                             const float* __restrict__ w,
                                             unsigned short* __restrict__ Qb,
                                             unsigned short* __restrict__ Kb,
                                             unsigned short* __restrict__ Vf) {
    __shared__ unsigned short ldsT[64 * 136];
    const int tid = threadIdx.x;
    const int t0 = blockIdx.x * 64;
    const int b = t0 >> 12;
    const int s0 = t0 & 4095;

    {
        const int t = tid & 63;
        const int cg = (tid >> 6) * 32;
        const float* xp = x + ((size_t)b * 128 + cg) * 4096 + s0 + t;
#pragma unroll
        for (int i = 0; i < 32; ++i)
            ldsT[t * 136 + cg + i] = f2bf(xp[(size_t)i * 4096]);
    }
    __syncthreads();

    const int lane = tid & 63;
    const int wv = tid >> 6;
    const int ln = lane & 15, lg = lane >> 4;

    for (int os = 0; os < 6; ++os) {
        const int ow = os * 64 + wv * 16;

        s16x8 aW[4];
#pragma unroll
        for (int ks = 0; ks < 4; ++ks) {
            const float* wp = w + (size_t)(ow + ln) * 128 + ks * 32 + lg * 8;
            s16x8 a;
#pragma unroll
            for (int j = 0; j < 8; ++j) a[j] = (short)f2bf(wp[j]);
            aW[ks] = a;
        }

        f32x4 acc[4] = {{0, 0, 0, 0}, {0, 0, 0, 0}, {0, 0, 0, 0}, {0, 0, 0, 0}};
#pragma unroll
        for (int ts = 0; ts < 4; ++ts) {
#pragma unroll
            for (int ks = 0; ks < 4; ++ks) {
                s16x8 bx = *(const s16x8*)&ldsT[(ts * 16 + ln) * 136 + ks * 32 + lg * 8];
                acc[ts] = MFMA16(aW[ks], bx, acc[ts]);
            }
        }

#pragma unroll
        for (int ts = 0; ts < 4; ++ts) {
            const int s = s0 + ts * 16 + ln;
#pragma unroll
            for (int r = 0; r < 4; ++r) {
                const int o = ow + lg * 4 + r;
                const float v = acc[ts][r];
                if (o < 128) {
                    const int h = o >> 5, d = o & 31;
                    Qb[((size_t)(b * 4 + h) * 4096 + s) * 32 + d] = f2bf(v * (SCALE * LOG2E));
                } else if (o < 256) {
                    const int oo = o - 128, h = oo >> 5, d = oo & 31;
                    const int js = s & 31, g = js >> 3, r4 = js & 7;
                    const int slot = (r4 < 4) ? (g * 4 + r4) : (16 + g * 4 + (r4 - 4));
                    const int sp = (s & ~31) | slot;
                    Kb[((size_t)(b * 4 + h) * 4096 + sp) * 32 + d] = f2bf(v);
                } else {
                    const int oo = o - 256, h = oo >> 5, d = oo & 31;
                    const int bh = b * 4 + h;
                    const int jb = s >> 5, js = s & 31;
                    const int lanep = (js >> 3) * 16 + (d & 15);
                    const size_t idx =
                        ((((size_t)bh * 128 + jb) * 2 + (d >> 4)) * 64 + lanep) * 8 + (js & 7);
                    Vf[idx] = f2bf(v);
                }
            }
        }
    }
}

// ---------------------------------------------------------------------------
// K2: fused attention — BYTE-IDENTICAL to passing R13 (52 us).
// grid (16 q-tiles of 256, 16 bh), block 512 (8 waves x 32 q-rows).
// Block-shared LDS K/V staging, 32 tiles of 128 keys, double-buffered,
// linear conflict-free staging/reads. No cross-wave combine.
// ---------------------------------------------------------------------------
__global__ __launch_bounds__(512) void k_attn(const unsigned short* __restrict__ Qb,
                                              const unsigned short* __restrict__ Kb,
                                              const unsigned short* __restrict__ Vf,
                                              unsigned short* __restrict__ att) {
    __shared__ __align__(16) char lds[2][16384];  // per buf: K 8KB | V 8KB
    const int tid = threadIdx.x;
    const int lane = tid & 63;
    const int wv = tid >> 6;  // 0..7
    const int ln = lane & 15, lg = lane >> 4;
    const int bh = blockIdx.y;
    const int i0 = blockIdx.x * 256 + wv * 32;  // this wave's 32 q rows
    const size_t base = (size_t)bh * 4096 * 32;

    // B-frags Q: rows i0+ln (qs=0) and i0+16+ln (qs=1), k = 8lg+m
    const s16x8 bQ0 = *(const s16x8*)(Qb + base + (size_t)(i0 + ln) * 32 + lg * 8);
    const s16x8 bQ1 = *(const s16x8*)(Qb + base + (size_t)(i0 + 16 + ln) * 32 + lg * 8);

    // global tile sources (each 128-key tile = contiguous 8KB in both arrays)
    const char* gK = (const char*)Kb + base * 2;  // bh*262144 bytes
    const char* gV = (const char*)Vf + (size_t)bh * 262144;

    const f32x4 zf = {0.f, 0.f, 0.f, 0.f};
    f32x4 acc00 = zf, acc01 = zf, acc10 = zf, acc11 = zf;  // [qs][dhalf]
    float lsum0 = 0.f, lsum1 = 0.f;

    auto body = [&](s16x8 cK0, s16x8 cK1, s16x8 cV0, s16x8 cV1) {
        const f32x4 S00 = MFMA16(cK0, bQ0, zf);
        const f32x4 S01 = MFMA16(cK1, bQ0, zf);
        const f32x4 S10 = MFMA16(cK0, bQ1, zf);
        const f32x4 S11 = MFMA16(cK1, bQ1, zf);
        float p00[4], p01[4], p10[4], p11[4];
#pragma unroll
        for (int r = 0; r < 4; ++r) {
            p00[r] = fexp2(S00[r]);
            p01[r] = fexp2(S01[r]);
            p10[r] = fexp2(S10[r]);
            p11[r] = fexp2(S11[r]);
        }
        lsum0 += ((p00[0] + p00[1]) + (p00[2] + p00[3])) + ((p01[0] + p01[1]) + (p01[2] + p01[3]));
        lsum1 += ((p10[0] + p10[1]) + (p10[2] + p10[3])) + ((p11[0] + p11[1]) + (p11[2] + p11[3]));
        u32x4 a0, a1;
        a0.x = cvtpk(p00[0], p00[1]);
        a0.y = cvtpk(p00[2], p00[3]);
        a0.z = cvtpk(p01[0], p01[1]);
        a0.w = cvtpk(p01[2], p01[3]);
        a1.x = cvtpk(p10[0], p10[1]);
        a1.y = cvtpk(p10[2], p10[3]);
        a1.z = cvtpk(p11[0], p11[1]);
        a1.w = cvtpk(p11[2], p11[3]);
        const s16x8 aP0 = __builtin_bit_cast(s16x8, a0);
        const s16x8 aP1 = __builtin_bit_cast(s16x8, a1);
        acc00 = MFMA16(aP0, cV0, acc00);
        acc01 = MFMA16(aP0, cV1, acc01);
        acc10 = MFMA16(aP1, cV0, acc10);
        acc11 = MFMA16(aP1, cV1, acc11);
    };

    // compute 4 x 32-key groups from LDS buffer `buf`
    auto COMPUTE = [&](int buf) {
        const char* kb = lds[buf];
        const char* vb = lds[buf] + 8192;
#pragma unroll
        for (int ii = 0; ii < 4; ++ii) {
            const s16x8 cK0 = *(const s16x8*)(kb + ii * 2048 + ln * 64 + lg * 16);
            const s16x8 cK1 = *(const s16x8*)(kb + ii * 2048 + 1024 + ln * 64 + lg * 16);
            const s16x8 cV0 = *(const s16x8*)(vb + ii * 2048 + lane * 16);
            const s16x8 cV1 = *(const s16x8*)(vb + ii * 2048 + 1024 + lane * 16);
            body(cK0, cK1, cV0, cV1);
        }
    };

    // ---- staged main loop: 32 tiles of 128 keys ----
    s16x8 kr = *(const s16x8*)(gK + tid * 16);
    s16x8 vr = *(const s16x8*)(gV + tid * 16);
    *(s16x8*)(lds[0] + tid * 16) = kr;
    *(s16x8*)(lds[0] + 8192 + tid * 16) = vr;
    __syncthreads();
    kr = *(const s16x8*)(gK + 8192 + tid * 16);  // tile 1 in flight
    vr = *(const s16x8*)(gV + 8192 + tid * 16);

    for (int t = 0; t < 32; ++t) {
        COMPUTE(t & 1);
        if (t < 31) {
            *(s16x8*)(lds[(t + 1) & 1] + tid * 16) = kr;
            *(s16x8*)(lds[(t + 1) & 1] + 8192 + tid * 16) = vr;
            if (t < 30) {
                kr = *(const s16x8*)(gK + (size_t)(t + 2) * 8192 + tid * 16);
                vr = *(const s16x8*)(gV + (size_t)(t + 2) * 8192 + tid * 16);
            }
        }
        __syncthreads();
    }

    // ---- epilogue: full row sums in-wave (no cross-wave combine) ----
    lsum0 += __shfl_xor(lsum0, 16);
    lsum0 += __shfl_xor(lsum0, 32);
    lsum1 += __shfl_xor(lsum1, 16);
    lsum1 += __shfl_xor(lsum1, 32);
    const int b = bh >> 2, h = bh & 3;
#pragma unroll
    for (int r = 0; r < 4; ++r) {
        const float rs0 = __shfl(lsum0, 4 * lg + r);  // q row 4lg+r (qs=0)
        const float rs1 = __shfl(lsum1, 4 * lg + r);  // q row 4lg+r (qs=1)
        const float ri0 = 1.0f / rs0;
        const float ri1 = 1.0f / rs1;
        const int q0 = i0 + lg * 4 + r;
        const int q1 = i0 + 16 + lg * 4 + r;
        const size_t off0 = ((size_t)b * 4096 + q0) * 128 + h * 32;
        const size_t off1 = ((size_t)b * 4096 + q1) * 128 + h * 32;
        att[off0 + ln] = f2bf(acc00[r] * ri0);
        att[off0 + 16 + ln] = f2bf(acc01[r] * ri0);
        att[off1 + ln] = f2bf(acc10[r] * ri1);
        att[off1 + 16 + ln] = f2bf(acc11[r] * ri1);
    }
}

// ---------------------------------------------------------------------------
// K3: out projection. THIS ROUND: grid 256 (no y); block loops both o-tiles
// so att is fetched from HBM/L2 once (second pass hits L1). Inner code
// identical to R13's.
// ---------------------------------------------------------------------------
__global__ __launch_bounds__(256) void k_out(const unsigned short* __restrict__ att,
                                             const float* __restrict__ w,
                                             const float* __restrict__ bias,
                                             float* __restrict__ out) {
    const int tid = threadIdx.x;
    const int lane = tid & 63;
    const int wv = tid >> 6;
    const int ln = lane & 15, lg = lane >> 4;
    const int t0 = blockIdx.x * 64;
    const int b = t0 >> 12, s0 = t0 & 4095;

    for (int os = 0; os < 2; ++os) {
        const int ow = os * 64 + wv * 16;

        s16x8 aW[4];
#pragma unroll
        for (int ks = 0; ks < 4; ++ks) {
            const float* wp = w + (size_t)(ow + ln) * 128 + ks * 32 + lg * 8;
            s16x8 a;
#pragma unroll
            for (int j = 0; j < 8; ++j) a[j] = (short)f2bf(wp[j]);
            aW[ks] = a;
        }

        f32x4 acc[4] = {{0, 0, 0, 0}, {0, 0, 0, 0}, {0, 0, 0, 0}, {0, 0, 0, 0}};
#pragma unroll
        for (int ts = 0; ts < 4; ++ts) {
#pragma unroll
            for (int ks = 0; ks < 4; ++ks) {
                s16x8 bx =
                    *(const s16x8*)(att + ((size_t)t0 + ts * 16 + ln) * 128 + ks * 32 + lg * 8);
                acc[ts] = MFMA16(aW[ks], bx, acc[ts]);
            }
        }

#pragma unroll
        for (int ts = 0; ts < 4; ++ts) {
            const int s = s0 + ts * 16 + ln;
#pragma unroll
            for (int r = 0; r < 4; ++r) {
                const int o = ow + lg * 4 + r;
                out[((size_t)b * 128 + o) * 4096 + s] = acc[ts][r] + bias[o];
            }
        }
    }
}

// ---------------------------------------------------------------------------
extern "C" void kernel_launch(void* const* d_in, const int* in_sizes, int n_in,
                              void* d_out, int out_size, void* d_ws, size_t ws_size,
                              hipStream_t stream) {
    const float* x = (const float*)d_in[0];
    const float* w_qkv = (const float*)d_in[1];
    const float* w_out = (const float*)d_in[2];
    const float* b_out = (const float*)d_in[3];
    float* out = (float*)d_out;

    unsigned short* Qb = (unsigned short*)d_ws;               // 4 MiB
    unsigned short* Kb = Qb + (size_t)16 * 4096 * 32;         // 4 MiB (slot-permuted)
    unsigned short* Vf = Kb + (size_t)16 * 4096 * 32;         // 4 MiB (fragment-major)
    unsigned short* att = Vf + (size_t)16 * 4096 * 32;        // 4 MiB

    k_qkv<<<256, 256, 0, stream>>>(x, w_qkv, Qb, Kb, Vf);
    k_attn<<<dim3(16, 16), 512, 0, stream>>>(Qb, Kb, Vf, att);
    k_out<<<256, 256, 0, stream>>>(att, w_out, b_out, out);
}

// Round 16
// 70.283 us; speedup vs baseline: 2.8778x; 1.0775x over previous
//
#include <hip/hip_runtime.h>

typedef float f32x4 __attribute__((ext_vector_type(4)));
typedef short s16x8 __attribute__((ext_vector_type(8)));
typedef unsigned int u32;
typedef unsigned int u32x4 __attribute__((ext_vector_type(4)));

#define SCALE 0.17677669529663687f
#define LOG2E 1.4426950408889634f

__device__ __forceinline__ unsigned short f2bf(float f) {
    unsigned u = __builtin_bit_cast(unsigned, f);
    u += 0x7fffu + ((u >> 16) & 1u);
    return (unsigned short)(u >> 16);
}

__device__ __forceinline__ float fexp2(float x) {
#if __has_builtin(__builtin_amdgcn_exp2f)
    return __builtin_amdgcn_exp2f(x);
#else
    return exp2f(x);
#endif
}

// packed f32 pair -> bf16x2 (RNE), dst.lo = lo
__device__ __forceinline__ u32 cvtpk(float lo, float hi) {
    u32 r;
    asm("v_cvt_pk_bf16_f32 %0, %1, %2" : "=v"(r) : "v"(lo), "v"(hi));
    return r;
}

#define MFMA16(a, b, c) __builtin_amdgcn_mfma_f32_16x16x32_bf16((a), (b), (c), 0, 0, 0)

// ---------------------------------------------------------------------------
// K1: qkv projection. grid (256, 6) for occupancy (24 waves/CU); stage/MFMA
// code identical to R13. NEW: coalesced-store epilogue — acc goes to LDS
// (bf16, reusing the x-stage buffer after a barrier), then 512x16B chunks are
// written out as global_store_dwordx4 (256B contiguous runs). Values and
// destinations bit-identical to R13 (absmax is a checksum).
// Q [bh][tok][32] pre-scaled; K slot-permuted; V fragment-major.
// ---------------------------------------------------------------------------
__global__ __launch_bounds__(256) void k_qkv(const float* __restrict__ x,
                                             const float* __restrict__ w,
                                             unsigned short* __restrict__ Qb,
                                             unsigned short* __restrict__ Kb,
                                             unsigned short* __restrict__ Vf) {
    __shared__ __align__(16) unsigned short ldsBuf[64 * 136];  // x^T stage, then out-tile
    const int tid = threadIdx.x;
    const int t0 = blockIdx.x * 64;
    const int os = blockIdx.y;  // 0..5: 0-1 Q, 2-3 K, 4-5 V
    const int b = t0 >> 12;
    const int s0 = t0 & 4095;

    {
        const int t = tid & 63;
        const int cg = (tid >> 6) * 32;
        const float* xp = x + ((size_t)b * 128 + cg) * 4096 + s0 + t;
#pragma unroll
        for (int i = 0; i < 32; ++i)
            ldsBuf[t * 136 + cg + i] = f2bf(xp[(size_t)i * 4096]);
    }
    __syncthreads();

    const int lane = tid & 63;
    const int wv = tid >> 6;
    const int ln = lane & 15, lg = lane >> 4;
    const int ow = os * 64 + wv * 16;

    s16x8 aW[4];
#pragma unroll
    for (int ks = 0; ks < 4; ++ks) {
        const float* wp = w + (size_t)(ow + ln) * 128 + ks * 32 + lg * 8;
        s16x8 a;
#pragma unroll
        for (int j = 0; j < 8; ++j) a[j] = (short)f2bf(wp[j]);
        aW[ks] = a;
    }

    f32x4 acc[4] = {{0, 0, 0, 0}, {0, 0, 0, 0}, {0, 0, 0, 0}, {0, 0, 0, 0}};
#pragma unroll
    for (int ts = 0; ts < 4; ++ts) {
#pragma unroll
        for (int ks = 0; ks < 4; ++ks) {
            s16x8 bx = *(const s16x8*)&ldsBuf[(ts * 16 + ln) * 136 + ks * 32 + lg * 8];
            acc[ts] = MFMA16(aW[ks], bx, acc[ts]);
        }
    }

    __syncthreads();  // x^T reads done; reuse ldsBuf as the output tile

    const bool isQ = (os < 2);
    // acc -> LDS tile, pitch 72 shorts (16B-aligned rows).
    // Q/K: [tok][chan]  (layout B);  V: [chan][tok]  (layout A)
#pragma unroll
    for (int ts = 0; ts < 4; ++ts) {
#pragma unroll
        for (int r = 0; r < 4; ++r) {
            const int o_l = wv * 16 + lg * 4 + r;  // 0..63 (channel within tile)
            const int s_l = ts * 16 + ln;          // 0..63 (token within tile)
            float v = acc[ts][r];
            if (isQ) v *= (SCALE * LOG2E);
            const unsigned short hv = f2bf(v);
            if (os < 4)
                ldsBuf[s_l * 72 + o_l] = hv;
            else
                ldsBuf[o_l * 72 + s_l] = hv;
        }
    }
    __syncthreads();

    // vectorized write-out: 512 chunks of 16B (2 per thread)
    if (os < 4) {
#pragma unroll
        for (int cc = 0; cc < 2; ++cc) {
            const int idx = tid + cc * 256;
            const int oct = idx & 3;         // d octet
            const int s_l = (idx >> 2) & 63; // token
            const int hh = idx >> 8;         // head half (0/1)
            const s16x8 v = *(const s16x8*)&ldsBuf[s_l * 72 + hh * 32 + oct * 8];
            if (isQ) {
                const int h = os * 2 + hh;
                *(s16x8*)(Qb + ((size_t)(b * 4 + h) * 4096 + s0 + s_l) * 32 + oct * 8) = v;
            } else {
                const int h = (os - 2) * 2 + hh;
                const int js = s_l & 31, g = js >> 3, r4 = js & 7;
                const int slot = (r4 < 4) ? (g * 4 + r4) : (16 + g * 4 + (r4 - 4));
                const int sp = s0 + (s_l & ~31) + slot;
                *(s16x8*)(Kb + ((size_t)(b * 4 + h) * 4096 + sp) * 32 + oct * 8) = v;
            }
        }
    } else {
#pragma unroll
        for (int cc = 0; cc < 2; ++cc) {
            const int idx = tid + cc * 256;
            const int d15 = idx & 15;
            const int dh = (idx >> 4) & 1;
            const int js8 = (idx >> 5) & 3;
            const int jb = (idx >> 7) & 1;
            const int hh = idx >> 8;
            const int d = dh * 16 + d15;
            const int o_l = hh * 32 + d;  // channel within this V tile
            const s16x8 v = *(const s16x8*)&ldsBuf[o_l * 72 + jb * 32 + js8 * 8];
            const int hv = (os - 4) * 2 + hh;
            const int jb_g = (s0 >> 5) + jb;
            *(s16x8*)(Vf +
                      ((((size_t)(b * 4 + hv) * 128 + jb_g) * 2 + dh) * 64 + js8 * 16 + d15) * 8) = v;
        }
    }
}

// ---------------------------------------------------------------------------
// K2: fused attention — BYTE-IDENTICAL to passing R13 (52 us). FROZEN.
// grid (16 q-tiles of 256, 16 bh), block 512 (8 waves x 32 q-rows).
// ---------------------------------------------------------------------------
__global__ __launch_bounds__(512) void k_attn(const unsigned short* __restrict__ Qb,
                                              const unsigned short* __restrict__ Kb,
                                              const unsigned short* __restrict__ Vf,
                                              unsigned short* __restrict__ att) {
    __shared__ __align__(16) char lds[2][16384];  // per buf: K 8KB | V 8KB
    const int tid = threadIdx.x;
    const int lane = tid & 63;
    const int wv = tid >> 6;  // 0..7
    const int ln = lane & 15, lg = lane >> 4;
    const int bh = blockIdx.y;
    const int i0 = blockIdx.x * 256 + wv * 32;  // this wave's 32 q rows
    const size_t base = (size_t)bh * 4096 * 32;

    // B-frags Q: rows i0+ln (qs=0) and i0+16+ln (qs=1), k = 8lg+m
    const s16x8 bQ0 = *(const s16x8*)(Qb + base + (size_t)(i0 + ln) * 32 + lg * 8);
    const s16x8 bQ1 = *(const s16x8*)(Qb + base + (size_t)(i0 + 16 + ln) * 32 + lg * 8);

    // global tile sources (each 128-key tile = contiguous 8KB in both arrays)
    const char* gK = (const char*)Kb + base * 2;  // bh*262144 bytes
    const char* gV = (const char*)Vf + (size_t)bh * 262144;

    const f32x4 zf = {0.f, 0.f, 0.f, 0.f};
    f32x4 acc00 = zf, acc01 = zf, acc10 = zf, acc11 = zf;  // [qs][dhalf]
    float lsum0 = 0.f, lsum1 = 0.f;

    auto body = [&](s16x8 cK0, s16x8 cK1, s16x8 cV0, s16x8 cV1) {
        const f32x4 S00 = MFMA16(cK0, bQ0, zf);
        const f32x4 S01 = MFMA16(cK1, bQ0, zf);
        const f32x4 S10 = MFMA16(cK0, bQ1, zf);
        const f32x4 S11 = MFMA16(cK1, bQ1, zf);
        float p00[4], p01[4], p10[4], p11[4];
#pragma unroll
        for (int r = 0; r < 4; ++r) {
            p00[r] = fexp2(S00[r]);
            p01[r] = fexp2(S01[r]);
            p10[r] = fexp2(S10[r]);
            p11[r] = fexp2(S11[r]);
        }
        lsum0 += ((p00[0] + p00[1]) + (p00[2] + p00[3])) + ((p01[0] + p01[1]) + (p01[2] + p01[3]));
        lsum1 += ((p10[0] + p10[1]) + (p10[2] + p10[3])) + ((p11[0] + p11[1]) + (p11[2] + p11[3]));
        u32x4 a0, a1;
        a0.x = cvtpk(p00[0], p00[1]);
        a0.y = cvtpk(p00[2], p00[3]);
        a0.z = cvtpk(p01[0], p01[1]);
        a0.w = cvtpk(p01[2], p01[3]);
        a1.x = cvtpk(p10[0], p10[1]);
        a1.y = cvtpk(p10[2], p10[3]);
        a1.z = cvtpk(p11[0], p11[1]);
        a1.w = cvtpk(p11[2], p11[3]);
        const s16x8 aP0 = __builtin_bit_cast(s16x8, a0);
        const s16x8 aP1 = __builtin_bit_cast(s16x8, a1);
        acc00 = MFMA16(aP0, cV0, acc00);
        acc01 = MFMA16(aP0, cV1, acc01);
        acc10 = MFMA16(aP1, cV0, acc10);
        acc11 = MFMA16(aP1, cV1, acc11);
    };

    // compute 4 x 32-key groups from LDS buffer `buf`
    auto COMPUTE = [&](int buf) {
        const char* kb = lds[buf];
        const char* vb = lds[buf] + 8192;
#pragma unroll
        for (int ii = 0; ii < 4; ++ii) {
            const s16x8 cK0 = *(const s16x8*)(kb + ii * 2048 + ln * 64 + lg * 16);
            const s16x8 cK1 = *(const s16x8*)(kb + ii * 2048 + 1024 + ln * 64 + lg * 16);
            const s16x8 cV0 = *(const s16x8*)(vb + ii * 2048 + lane * 16);
            const s16x8 cV1 = *(const s16x8*)(vb + ii * 2048 + 1024 + lane * 16);
            body(cK0, cK1, cV0, cV1);
        }
    };

    // ---- staged main loop: 32 tiles of 128 keys ----
    s16x8 kr = *(const s16x8*)(gK + tid * 16);
    s16x8 vr = *(const s16x8*)(gV + tid * 16);
    *(s16x8*)(lds[0] + tid * 16) = kr;
    *(s16x8*)(lds[0] + 8192 + tid * 16) = vr;
    __syncthreads();
    kr = *(const s16x8*)(gK + 8192 + tid * 16);  // tile 1 in flight
    vr = *(const s16x8*)(gV + 8192 + tid * 16);

    for (int t = 0; t < 32; ++t) {
        COMPUTE(t & 1);
        if (t < 31) {
            *(s16x8*)(lds[(t + 1) & 1] + tid * 16) = kr;
            *(s16x8*)(lds[(t + 1) & 1] + 8192 + tid * 16) = vr;
            if (t < 30) {
                kr = *(const s16x8*)(gK + (size_t)(t + 2) * 8192 + tid * 16);
                vr = *(const s16x8*)(gV + (size_t)(t + 2) * 8192 + tid * 16);
            }
        }
        __syncthreads();
    }

    // ---- epilogue: full row sums in-wave (no cross-wave combine) ----
    lsum0 += __shfl_xor(lsum0, 16);
    lsum0 += __shfl_xor(lsum0, 32);
    lsum1 += __shfl_xor(lsum1, 16);
    lsum1 += __shfl_xor(lsum1, 32);
    const int b = bh >> 2, h = bh & 3;
#pragma unroll
    for (int r = 0; r < 4; ++r) {
        const float rs0 = __shfl(lsum0, 4 * lg + r);  // q row 4lg+r (qs=0)
        const float rs1 = __shfl(lsum1, 4 * lg + r);  // q row 4lg+r (qs=1)
        const float ri0 = 1.0f / rs0;
        const float ri1 = 1.0f / rs1;
        const int q0 = i0 + lg * 4 + r;
        const int q1 = i0 + 16 + lg * 4 + r;
        const size_t off0 = ((size_t)b * 4096 + q0) * 128 + h * 32;
        const size_t off1 = ((size_t)b * 4096 + q1) * 128 + h * 32;
        att[off0 + ln] = f2bf(acc00[r] * ri0);
        att[off0 + 16 + ln] = f2bf(acc01[r] * ri0);
        att[off1 + ln] = f2bf(acc10[r] * ri1);
        att[off1 + 16 + ln] = f2bf(acc11[r] * ri1);
    }
}

// ---------------------------------------------------------------------------
// K3: out projection — R13 version (grid (256,2), 8 waves/CU).
// ---------------------------------------------------------------------------
__global__ __launch_bounds__(256) void k_out(const unsigned short* __restrict__ att,
                                             const float* __restrict__ w,
                                             const float* __restrict__ bias,
                                             float* __restrict__ out) {
    const int tid = threadIdx.x;
    const int lane = tid & 63;
    const int wv = tid >> 6;
    const int ln = lane & 15, lg = lane >> 4;
    const int t0 = blockIdx.x * 64;
    const int o0 = blockIdx.y * 64;
    const int ow = o0 + wv * 16;
    const int b = t0 >> 12, s0 = t0 & 4095;

    s16x8 aW[4];
#pragma unroll
    for (int ks = 0; ks < 4; ++ks) {
        const float* wp = w + (size_t)(ow + ln) * 128 + ks * 32 + lg * 8;
        s16x8 a;
#pragma unroll
        for (int j = 0; j < 8; ++j) a[j] = (short)f2bf(wp[j]);
        aW[ks] = a;
    }

    f32x4 acc[4] = {{0, 0, 0, 0}, {0, 0, 0, 0}, {0, 0, 0, 0}, {0, 0, 0, 0}};
#pragma unroll
    for (int ts = 0; ts < 4; ++ts) {
#pragma unroll
        for (int ks = 0; ks < 4; ++ks) {
            s16x8 bx = *(const s16x8*)(att + ((size_t)t0 + ts * 16 + ln) * 128 + ks * 32 + lg * 8);
            acc[ts] = MFMA16(aW[ks], bx, acc[ts]);
        }
    }

#pragma unroll
    for (int ts = 0; ts < 4; ++ts) {
        const int s = s0 + ts * 16 + ln;
#pragma unroll
        for (int r = 0; r < 4; ++r) {
            const int o = ow + lg * 4 + r;
            out[((size_t)b * 128 + o) * 4096 + s] = acc[ts][r] + bias[o];
        }
    }
}

// ---------------------------------------------------------------------------
extern "C" void kernel_launch(void* const* d_in, const int* in_sizes, int n_in,
                              void* d_out, int out_size, void* d_ws, size_t ws_size,
                              hipStream_t stream) {
    const float* x = (const float*)d_in[0];
    const float* w_qkv = (const float*)d_in[1];
    const float* w_out = (const float*)d_in[2];
    const float* b_out = (const float*)d_in[3];
    float* out = (float*)d_out;

    unsigned short* Qb = (unsigned short*)d_ws;               // 4 MiB
    unsigned short* Kb = Qb + (size_t)16 * 4096 * 32;         // 4 MiB (slot-permuted)
    unsigned short* Vf = Kb + (size_t)16 * 4096 * 32;         // 4 MiB (fragment-major)
    unsigned short* att = Vf + (size_t)16 * 4096 * 32;        // 4 MiB

    k_qkv<<<dim3(256, 6), 256, 0, stream>>>(x, w_qkv, Qb, Kb, Vf);
    k_attn<<<dim3(16, 16), 512, 0, stream>>>(Qb, Kb, Vf, att);
    k_out<<<dim3(256, 2), 256, 0, stream>>>(att, w_out, b_out, out);
}